// Round 18
// baseline (288.439 us; speedup 1.0000x reference)
//
#include <hip/hip_runtime.h>
#include <hip/hip_bf16.h>
#include <stdint.h>
#include <string.h>

using bf16 = __hip_bfloat16;
typedef __attribute__((ext_vector_type(8))) short bf16x8;   // 8 bf16 (4 VGPRs) MFMA A/B frag
typedef __attribute__((ext_vector_type(4))) float f32x4;    // MFMA C/D frag

#define DEV static __device__ __forceinline__

DEV bf16 tobf(float f) { return __float2bfloat16(f); }
DEV float tof(bf16 h) { return __bfloat162float(h); }

// async global->LDS, 16B per lane. LDS dest semantics: wave-uniform base + lane*16.
DEV void gload_lds16(const void* g, void* l) {
  __builtin_amdgcn_global_load_lds((__attribute__((address_space(1))) void*)g,
                                   (__attribute__((address_space(3))) void*)l,
                                   16, 0, 0);
}

// ---------------- fused prep kernel ----------------
// One flat grid, 5152 blocks x 256 threads:
//   t <  2560 : 64x64 transpose+cast tiles over {Wq,Wk,Wv,Wo} -> WT / WoT
//   t <  4608 : cast X fp32 -> bf16 (4 float4/thread)
//   t <  5120 : rope cos/sin tables (4 s-rows/block)
//   else      : Wg1/Wg2 transpose into WT rows 3072..3103
__global__ __launch_bounds__(256) void prep_all_k(
    const float* __restrict__ X, const int* __restrict__ pos,
    const float* __restrict__ Wq, const float* __restrict__ Wk,
    const float* __restrict__ Wv, const float* __restrict__ Wo,
    const float* __restrict__ Wg1, const float* __restrict__ Wg2,
    bf16* __restrict__ WT, bf16* __restrict__ WoT, bf16* __restrict__ Xbf,
    float* __restrict__ cosT, float* __restrict__ sinT) {
  __shared__ float tile[64][65];
  const int t = blockIdx.x, tid = threadIdx.x;
  if (t < 2560) {
    const float* src; bf16* dst; int N, kb, nb;
    if (t < 1024)      { src = Wq; dst = WT;                  N = 2048; kb = (t >> 5) << 6;          nb = (t & 31) << 6; }
    else if (t < 1280) { int l = t - 1024; src = Wk; dst = WT + 2048ull * 2048; N = 512; kb = (l >> 3) << 6; nb = (l & 7) << 6; }
    else if (t < 1536) { int l = t - 1280; src = Wv; dst = WT + 2560ull * 2048; N = 512; kb = (l >> 3) << 6; nb = (l & 7) << 6; }
    else               { int l = t - 1536; src = Wo; dst = WoT;                N = 2048; kb = (l >> 5) << 6; nb = (l & 31) << 6; }
    const int c = tid & 63, r0 = tid >> 6;
#pragma unroll
    for (int i = 0; i < 16; i++) {
      int r = i * 4 + r0;
      tile[r][c] = src[(size_t)(kb + r) * N + nb + c];
    }
    __syncthreads();
    const int q = tid & 7;
#pragma unroll
    for (int p = 0; p < 2; p++) {
      int n = p * 32 + (tid >> 3);
      bf16 pk[8];
#pragma unroll
      for (int j = 0; j < 8; j++) pk[j] = tobf(tile[q * 8 + j][n]);
      uint4 u; __builtin_memcpy(&u, pk, 16);
      *(uint4*)(dst + (size_t)(nb + n) * 2048 + kb + q * 8) = u;
    }
  } else if (t < 4608) {
    const int blk = t - 2560;
#pragma unroll
    for (int j = 0; j < 4; j++) {
      int idx = blk * 1024 + j * 256 + tid;
      float4 v = ((const float4*)X)[idx];
      bf16 p4[4] = {tobf(v.x), tobf(v.y), tobf(v.z), tobf(v.w)};
      uint2 p; __builtin_memcpy(&p, p4, 8);
      ((uint2*)Xbf)[idx] = p;
    }
  } else if (t < 5120) {
    const int blk = t - 4608;
    int s = blk * 4 + (tid >> 6), i = tid & 63;
    double inv = exp(-((double)(2 * i) / 128.0) * log(10000.0));
    float f = (float)pos[s] * (float)inv;
    cosT[s * 64 + i] = cosf(f);
    sinT[s * 64 + i] = sinf(f);
  } else {
    const int blk = t - 5120;
    int g = blk >> 4, r = blk & 15;
    const float* src = g ? Wg2 : Wg1;
    bf16* dst = WT + (size_t)(3072 + g * 16 + r) * 2048;
    for (int k = tid; k < 2048; k += 256) dst[k] = tobf(src[(size_t)k * 16 + r]);
  }
}

// ---------------- QKV+gates GEMM with fused RoPE: [qkv | g1t | g2t] = Xbf @ WT^T ----
// Q heads (bn<16) are additionally pre-scaled by 1/sqrt(128)*log2(e) so attention's
// QK^T lands directly in the log2 softmax domain (saves scale-mul + exp pre-mul there).
__global__ __launch_bounds__(256, 2) void gemm_qkv_k(
    const bf16* __restrict__ A, const bf16* __restrict__ Bt, bf16* __restrict__ qkv,
    float* __restrict__ g1t, float* __restrict__ g2t,
    const float* __restrict__ bg1, const float* __restrict__ bg2,
    const float* __restrict__ cosT, const float* __restrict__ sinT) {
  constexpr int BK = 32, K = 2048;
  __shared__ bf16 smem[16384];  // sA = smem[0..8191] (2 bufs), sB = smem[8192..16383]; ex = all
  const int tid = threadIdx.x, wave = tid >> 6, lane = tid & 63;
  const int lhi = lane >> 4, llo = lane & 15;
  const int wm = wave >> 1, wn = wave & 1;
  const int bid = blockIdx.x;
  const int swz = (bid & 7) * 100 + (bid >> 3);  // bijective: 800 = 8*100
  const int bm = swz & 31, bn = swz >> 5;        // bn in 0..24
  const bf16* Ag = A + (size_t)bm * 128 * K;
  const bf16* Bg = Bt + (size_t)bn * 128 * K;

  f32x4 acc[4][4];
#pragma unroll
  for (int m = 0; m < 4; m++)
#pragma unroll
    for (int n = 0; n < 4; n++) acc[m][n] = f32x4{0.f, 0.f, 0.f, 0.f};

  auto stage = [&](int buf, int kt) {
#pragma unroll
    for (int i = 0; i < 2; i++) {
      int c = i * 256 + tid, row = c >> 2, c8 = c & 3;
      gload_lds16(Ag + (size_t)row * K + kt * BK + c8 * 8, smem + buf * 4096 + c * 8);
    }
#pragma unroll
    for (int i = 0; i < 2; i++) {
      int c = i * 256 + tid, row = c >> 2, c8 = c & 3;
      gload_lds16(Bg + (size_t)row * K + kt * BK + c8 * 8, smem + 8192 + buf * 4096 + c * 8);
    }
  };

  const int NT = K / BK;
  stage(0, 0);
  for (int kt = 0; kt < NT; kt++) {
    __syncthreads();
    if (kt + 1 < NT) stage((kt + 1) & 1, kt + 1);
    const bf16* a_ = smem + (kt & 1) * 4096;
    const bf16* b_ = smem + 8192 + (kt & 1) * 4096;
    bf16x8 af[4], bfr[4];
#pragma unroll
    for (int m = 0; m < 4; m++)
      af[m] = *(const bf16x8*)&a_[(wm * 64 + m * 16 + llo) * BK + lhi * 8];
#pragma unroll
    for (int n = 0; n < 4; n++)
      bfr[n] = *(const bf16x8*)&b_[(wn * 64 + n * 16 + llo) * BK + lhi * 8];
#pragma unroll
    for (int m = 0; m < 4; m++)
#pragma unroll
      for (int n = 0; n < 4; n++)
        acc[m][n] = __builtin_amdgcn_mfma_f32_16x16x32_bf16(af[m], bfr[n], acc[m][n], 0, 0, 0);
  }

  if (bn < 24) {
    // stage full 128x128 tile as bf16 into LDS (over sA/sB)
    bf16* ex = smem;
    __syncthreads();  // all waves done reading sA/sB
#pragma unroll
    for (int m = 0; m < 4; m++)
#pragma unroll
      for (int n = 0; n < 4; n++) {
        int wrow = wm * 64 + m * 16 + lhi * 4;
        int wc = wn * 64 + n * 16 + llo;
#pragma unroll
        for (int r = 0; r < 4; r++) ex[(wrow + r) * 128 + wc] = tobf(acc[m][n][r]);
      }
    __syncthreads();
    if (bn < 20) {
      // RoPE: 128 rows x 8 lo-chunks (8 cols), 4 per thread.
      // Q heads: extra pre-scale by 1/sqrt(128)*log2(e) for log2-domain softmax.
      const float qs = (bn < 16) ? 0.12751651545f : 1.0f;
#pragma unroll
      for (int i = 0; i < 4; i++) {
        int c = i * 256 + tid, row = c >> 3, d0 = (c & 7) * 8;
        int token = bm * 128 + row, s = token & 2047;
        bf16x8 lo = *(const bf16x8*)&ex[row * 128 + d0];
        bf16x8 hi = *(const bf16x8*)&ex[row * 128 + d0 + 64];
        float4 ca = *(const float4*)(cosT + s * 64 + d0);
        float4 cb = *(const float4*)(cosT + s * 64 + d0 + 4);
        float4 sa = *(const float4*)(sinT + s * 64 + d0);
        float4 sb = *(const float4*)(sinT + s * 64 + d0 + 4);
        float cs[8] = {ca.x, ca.y, ca.z, ca.w, cb.x, cb.y, cb.z, cb.w};
        float sn[8] = {sa.x, sa.y, sa.z, sa.w, sb.x, sb.y, sb.z, sb.w};
        bf16x8 olo, ohi;
#pragma unroll
        for (int jj = 0; jj < 8; jj++) {
          float a = tof(((const bf16*)&lo)[jj]), b2 = tof(((const bf16*)&hi)[jj]);
          ((bf16*)&olo)[jj] = tobf((a * cs[jj] - b2 * sn[jj]) * qs);
          ((bf16*)&ohi)[jj] = tobf((b2 * cs[jj] + a * sn[jj]) * qs);
        }
        bf16* dst = qkv + (size_t)token * 3072 + bn * 128 + d0;
        *(uint4*)dst = *(const uint4*)&olo;
        *(uint4*)(dst + 64) = *(const uint4*)&ohi;
      }
    } else {
      // V: plain coalesced copy-out, 8 uint4 per thread
#pragma unroll
      for (int i = 0; i < 8; i++) {
        int c = i * 256 + tid, row = c >> 4, ch = c & 15;
        int token = bm * 128 + row;
        *(uint4*)(qkv + (size_t)token * 3072 + bn * 128 + ch * 8) =
            *(const uint4*)&ex[row * 128 + ch * 8];
      }
    }
  } else {
    const int r0 = bm * 128 + wm * 64, c0 = bn * 128 + wn * 64;
#pragma unroll
    for (int m = 0; m < 4; m++)
#pragma unroll
      for (int n = 0; n < 4; n++) {
        int col = c0 + n * 16 + llo;
#pragma unroll
        for (int r = 0; r < 4; r++) {
          int row = r0 + m * 16 + lhi * 4 + r;
          if (col >= 3072 && col < 3104) {
            int idx = col - 3072, hh = idx & 15;
            float b = (idx < 16) ? bg1[hh] : bg2[hh];
            float v = 1.f / (1.f + __expf(-(acc[m][n][r] + b)));
            ((idx < 16) ? g1t : g2t)[(size_t)hh * 4096 + row] = v;
          }
        }
      }
  }
}

// ---------------- output GEMM: C = A(4096xK) * Bt(2048xK)^T, fp32 out ----------------
__global__ __launch_bounds__(256, 2) void gemm_out_k(
    const bf16* __restrict__ A, const bf16* __restrict__ Bt, float* __restrict__ C,
    int N, int K) {
  constexpr int BK = 32;
  __shared__ bf16 sA[2][128 * BK];
  __shared__ bf16 sB[2][128 * BK];
  const int tid = threadIdx.x, wave = tid >> 6, lane = tid & 63;
  const int lhi = lane >> 4, llo = lane & 15;
  const int wm = wave >> 1, wn = wave & 1;
  const int bid = blockIdx.x;
  const int swz = (bid & 7) * 64 + (bid >> 3);  // bijective: 512 = 8*64
  const int bm = swz & 31, bn = swz >> 5;       // bn in 0..15
  const bf16* Ag = A + (size_t)bm * 128 * K;
  const bf16* Bg = Bt + (size_t)bn * 128 * K;

  f32x4 acc[4][4];
#pragma unroll
  for (int m = 0; m < 4; m++)
#pragma unroll
    for (int n = 0; n < 4; n++) acc[m][n] = f32x4{0.f, 0.f, 0.f, 0.f};

  auto stage = [&](int buf, int kt) {
#pragma unroll
    for (int i = 0; i < 2; i++) {
      int c = i * 256 + tid, row = c >> 2, c8 = c & 3;
      gload_lds16(Ag + (size_t)row * K + kt * BK + c8 * 8, &sA[buf][c * 8]);
    }
#pragma unroll
    for (int i = 0; i < 2; i++) {
      int c = i * 256 + tid, row = c >> 2, c8 = c & 3;
      gload_lds16(Bg + (size_t)row * K + kt * BK + c8 * 8, &sB[buf][c * 8]);
    }
  };

  const int NT = K / BK;
  stage(0, 0);
  for (int kt = 0; kt < NT; kt++) {
    __syncthreads();
    if (kt + 1 < NT) stage((kt + 1) & 1, kt + 1);
    const bf16* a_ = sA[kt & 1];
    const bf16* b_ = sB[kt & 1];
    bf16x8 af[4], bfr[4];
#pragma unroll
    for (int m = 0; m < 4; m++)
      af[m] = *(const bf16x8*)&a_[(wm * 64 + m * 16 + llo) * BK + lhi * 8];
#pragma unroll
    for (int n = 0; n < 4; n++)
      bfr[n] = *(const bf16x8*)&b_[(wn * 64 + n * 16 + llo) * BK + lhi * 8];
#pragma unroll
    for (int m = 0; m < 4; m++)
#pragma unroll
      for (int n = 0; n < 4; n++)
        acc[m][n] = __builtin_amdgcn_mfma_f32_16x16x32_bf16(af[m], bfr[n], acc[m][n], 0, 0, 0);
  }

  const int r0 = bm * 128 + wm * 64, c0 = bn * 128 + wn * 64;
#pragma unroll
  for (int m = 0; m < 4; m++)
#pragma unroll
    for (int n = 0; n < 4; n++)
#pragma unroll
      for (int r = 0; r < 4; r++)
        C[(size_t)(r0 + m * 16 + lhi * 4 + r) * N + (c0 + n * 16 + llo)] = acc[m][n][r];
}

// ---------------- shared attention epilogue: LN + g1 gate + coalesced store ----------------
DEV void finalize_store(const f32x4 (&o)[8], int wave, int lhi, int llo, int tid,
                        int h, int qt, size_t tok0,
                        const float* __restrict__ g1t, const float* __restrict__ lng,
                        const float* __restrict__ lnb, bf16* stg, bf16* __restrict__ aout) {
  float sum[4] = {0, 0, 0, 0}, sq[4] = {0, 0, 0, 0};
#pragma unroll
  for (int dt = 0; dt < 8; dt++)
#pragma unroll
    for (int r = 0; r < 4; r++) {
      float v = o[dt][r];
      sum[r] += v;
      sq[r] += v * v;
    }
  float mu[4], rstd[4];
#pragma unroll
  for (int r = 0; r < 4; r++) {
    float s1 = sum[r], s2 = sq[r];
    s1 += __shfl_xor(s1, 1); s1 += __shfl_xor(s1, 2); s1 += __shfl_xor(s1, 4); s1 += __shfl_xor(s1, 8);
    s2 += __shfl_xor(s2, 1); s2 += __shfl_xor(s2, 2); s2 += __shfl_xor(s2, 4); s2 += __shfl_xor(s2, 8);
    float m_ = s1 * (1.f / 128.f);
    float var = s2 * (1.f / 128.f) - m_ * m_;
    mu[r] = m_;
    rstd[r] = rsqrtf(var + 1e-5f);
  }
  __syncthreads();  // prior users of stg done
#pragma unroll
  for (int r = 0; r < 4; r++) {
    int lrow = wave * 16 + lhi * 4 + r;
    float gg = g1t[(size_t)h * 4096 + tok0 + qt * 64 + lrow];
#pragma unroll
    for (int dt = 0; dt < 8; dt++) {
      int d = dt * 16 + llo;
      float v = (o[dt][r] - mu[r]) * rstd[r] * lng[d] + lnb[d];
      stg[lrow * 128 + d] = tobf(v * gg);
    }
  }
  __syncthreads();
#pragma unroll
  for (int i = 0; i < 4; i++) {
    int c = i * 256 + tid, lr = c >> 4, c8 = c & 15;
    *(uint4*)(aout + (tok0 + qt * 64 + lr) * 2048 + h * 128 + c8 * 8) =
        *(const uint4*)&stg[lr * 128 + c8 * 8];
  }
}

// cumulative split count before qt (8-tile chunks): pid = pid_base(qt) + s, 80 total
DEV int pid_base(int qt) {
  return qt < 8 ? qt : qt < 16 ? 2 * qt - 8 : qt < 24 ? 3 * qt - 24 : 4 * qt - 48;
}

// LPT-ordered (qt,s) unit table, encoded qt*4+s. Full 8-tile chunks first, then
// remainder chunks by length descending (7..1).
__device__ const unsigned char UNIT_TAB[80] = {
  124,125,126,127,                          // qt31 x4 (len8)
  120,121,122, 116,117,118, 112,113,114,    // qt30..28 (len8)
  108,109,110, 104,105,106, 100,101,102,    // qt27..25
   96, 97, 98,  92, 93, 94,                 // qt24, qt23
   88, 89,  84, 85,  80, 81,  76, 77,       // qt22..19 (len8)
   72, 73,  68, 69,  64, 65,  60, 61,       // qt18..15
   56, 52, 48, 44, 40, 36, 32, 28,          // qt14..7 (len8, single/first)
  123, 90, 57, 24,                          // len7: (30,3)(22,2)(14,1)(6,0)
  119, 86, 53, 20,                          // len6
  115, 82, 49, 16,                          // len5
  111, 78, 45, 12,                          // len4
  107, 74, 41,  8,                          // len3
  103, 70, 37,  4,                          // len2
   99, 66, 33,  0                           // len1
};

// ---------------- split-K causal GQA attention: 2 q-heads, 8-tile LPT units ----------------
// R9 body + T5 s_setprio (R15) + bf16 partials (R17). Softmax in log2 domain:
// Q carries 1/sqrt(128)*log2(e) (folded in gemm_qkv), so p = exp2(sc - m) with no
// per-element scale-mul and no exp pre-mul. pML m is in log2 domain (combine matches).
__global__ __launch_bounds__(256, 2) void attn_split_k(
    const bf16* __restrict__ qkv, const float* __restrict__ g2t,
    const float* __restrict__ g1t, const float* __restrict__ lng,
    const float* __restrict__ lnb,
    bf16* __restrict__ pO, float* __restrict__ pML, bf16* __restrict__ aout) {
  constexpr int S = 2048, LD = 3072;
  const int bid = blockIdx.x;
  const int g = bid & 7, j = bid >> 3;
  const int hp = j & 1, u = j >> 1;
  const int e = UNIT_TAB[u];
  const int qt = e >> 2, s = e & 3;
  const int k0 = s * 8, k1 = min(s * 8 + 8, qt + 1);
  const bool partial = (qt >= 8);

  const int b = g >> 2, kvh = g & 3, h0 = kvh * 4 + hp * 2;
  const int tid = threadIdx.x, wave = tid >> 6, lane = tid & 63;
  const int lhi = lane >> 4, llo = lane & 15;
  const size_t tok0 = (size_t)b * S;

  __shared__ bf16 sK[64 * 128];      // [kv][d], XOR-swizzled ((row&7)<<3 on element idx)
  __shared__ bf16 sV[128 * 64];      // [d][kv] transposed, XOR-swizzled ((d&7)<<3)
  __shared__ bf16 sP[4][2][16][72];  // per-wave, per-head P tile, padded

  const int qrow0 = qt * 64 + wave * 16;

  bf16x8 qf[2][4];
#pragma unroll
  for (int hh = 0; hh < 2; hh++) {
    const bf16* qg = qkv + (tok0 + qrow0 + llo) * LD + (h0 + hh) * 128;
#pragma unroll
    for (int dc = 0; dc < 4; dc++) qf[hh][dc] = *(const bf16x8*)(qg + dc * 32 + lhi * 8);
  }

  f32x4 oacc[2][8];
#pragma unroll
  for (int hh = 0; hh < 2; hh++)
#pragma unroll
    for (int i = 0; i < 8; i++) oacc[hh][i] = f32x4{0.f, 0.f, 0.f, 0.f};
  float mrow[2][4], lrow[2][4];
#pragma unroll
  for (int hh = 0; hh < 2; hh++)
#pragma unroll
    for (int r = 0; r < 4; r++) { mrow[hh][r] = -1e30f; lrow[hh][r] = 0.f; }

  uint4 kreg[4];
  bf16x8 vreg[4];
  float gvreg[2];
  const int vdg = tid >> 4;   // d-group: 8 d elems
  const int vkg = tid & 15;   // kv-group: 4 kv rows

  auto issue_loads = [&](int kt) {
#pragma unroll
    for (int i = 0; i < 4; i++) {
      int c = i * 256 + tid, row = c >> 4, c8 = c & 15;
      kreg[i] = *(const uint4*)(qkv + (tok0 + kt * 64 + row) * LD + 2048 + kvh * 128 + c8 * 8);
    }
#pragma unroll
    for (int r = 0; r < 4; r++)
      vreg[r] = *(const bf16x8*)(qkv + (tok0 + kt * 64 + vkg * 4 + r) * LD + 2560 +
                                 kvh * 128 + vdg * 8);
#pragma unroll
    for (int hh = 0; hh < 2; hh++)
      gvreg[hh] = g2t[(size_t)(h0 + hh) * 4096 + tok0 + kt * 64 + lane];
  };

  auto write_lds = [&]() {
#pragma unroll
    for (int i = 0; i < 4; i++) {
      int c = i * 256 + tid, row = c >> 4, c8 = c & 15;
      int eidx = (row * 128 + c8 * 8) ^ ((row & 7) << 3);
      *(uint4*)&sK[eidx] = kreg[i];
    }
#pragma unroll
    for (int e2 = 0; e2 < 8; e2++) {
      int d = vdg * 8 + e2;          // d & 7 == e2
      uint32_t lo = (uint32_t)(unsigned short)vreg[0][e2] |
                    ((uint32_t)(unsigned short)vreg[1][e2] << 16);
      uint32_t hi = (uint32_t)(unsigned short)vreg[2][e2] |
                    ((uint32_t)(unsigned short)vreg[3][e2] << 16);
      int eidx = (d * 64 + vkg * 4) ^ (e2 << 3);
      uint2 pk; pk.x = lo; pk.y = hi;
      *(uint2*)&sV[eidx] = pk;
    }
  };

  issue_loads(k0);
  for (int kt = k0; kt < k1; kt++) {
    __syncthreads();  // previous tile's LDS reads complete before overwrite
    write_lds();      // vmcnt wait lands here (data long arrived)
    float gv0 = gvreg[0], gv1 = gvreg[1];
    if (kt + 1 < k1) issue_loads(kt + 1);  // registers only; in flight across barrier+compute
    __syncthreads();  // LDS writes visible

    const bool diag = (kt == qt);
#pragma unroll
    for (int hh = 0; hh < 2; hh++) {
      // ---- QK^T (T5: raise wave priority through the MFMA cluster) ----
      f32x4 sc[4];
      __builtin_amdgcn_s_setprio(1);
#pragma unroll
      for (int ct = 0; ct < 4; ct++) {
        f32x4 acc = f32x4{0.f, 0.f, 0.f, 0.f};
#pragma unroll
        for (int dc = 0; dc < 4; dc++) {
          int row = ct * 16 + llo;
          bf16x8 kf = *(const bf16x8*)&sK[(row * 128 + dc * 32 + lhi * 8) ^ ((row & 7) << 3)];
          acc = __builtin_amdgcn_mfma_f32_16x16x32_bf16(qf[hh][dc], kf, acc, 0, 0, 0);
        }
        sc[ct] = acc;
      }
      __builtin_amdgcn_s_setprio(0);
      // ---- causal mask + online softmax, log2 domain (exact defer-max) ----
      float pm[4] = {-1e30f, -1e30f, -1e30f, -1e30f};
#pragma unroll
      for (int ct = 0; ct < 4; ct++) {
        int kv = kt * 64 + ct * 16 + llo;
#pragma unroll
        for (int r = 0; r < 4; r++) {
          float s_ = sc[ct][r];
          if (diag && kv > qrow0 + lhi * 4 + r) s_ = -1e30f;
          sc[ct][r] = s_;
          pm[r] = fmaxf(pm[r], s_);
        }
      }
#pragma unroll
      for (int r = 0; r < 4; r++) {
        float v = pm[r];
        v = fmaxf(v, __shfl_xor(v, 1));
        v = fmaxf(v, __shfl_xor(v, 2));
        v = fmaxf(v, __shfl_xor(v, 4));
        v = fmaxf(v, __shfl_xor(v, 8));
        pm[r] = v;
      }
      int need = 0;
#pragma unroll
      for (int r = 0; r < 4; r++) need |= (pm[r] > mrow[hh][r]) ? 1 : 0;
      if (__any(need)) {
#pragma unroll
        for (int r = 0; r < 4; r++) {
          float mnew = fmaxf(mrow[hh][r], pm[r]);
          float al = exp2f(mrow[hh][r] - mnew);
          mrow[hh][r] = mnew;
          lrow[hh][r] *= al;
#pragma unroll
          for (int i = 0; i < 8; i++) oacc[hh][i][r] *= al;
        }
      }
      float gv = hh ? gv1 : gv0;
      float g2v[4];
#pragma unroll
      for (int ct = 0; ct < 4; ct++) g2v[ct] = __shfl(gv, ct * 16 + llo);
      float rs[4] = {0.f, 0.f, 0.f, 0.f};
#pragma unroll
      for (int ct = 0; ct < 4; ct++) {
#pragma unroll
        for (int r = 0; r < 4; r++) {
          float p = exp2f(sc[ct][r] - mrow[hh][r]);
          rs[r] += p;  // softmax denom uses UNGATED p
          sP[wave][hh][lhi * 4 + r][ct * 16 + llo] = tobf(p * g2v[ct]);
        }
      }
#pragma unroll
      for (int r = 0; r < 4; r++) {
        float v = rs[r];
        v += __shfl_xor(v, 1); v += __shfl_xor(v, 2); v += __shfl_xor(v, 4); v += __shfl_xor(v, 8);
        lrow[hh][r] += v;
      }
    }
    // ---- PV: both heads share each V fragment (T5 around MFMA cluster) ----
    __builtin_amdgcn_s_setprio(1);
#pragma unroll
    for (int kc = 0; kc < 2; kc++) {
      bf16x8 pf0 = *(const bf16x8*)&sP[wave][0][llo][kc * 32 + lhi * 8];
      bf16x8 pf1 = *(const bf16x8*)&sP[wave][1][llo][kc * 32 + lhi * 8];
#pragma unroll
      for (int dt = 0; dt < 8; dt++) {
        int d = dt * 16 + llo;
        bf16x8 vf = *(const bf16x8*)&sV[(d * 64 + kc * 32 + lhi * 8) ^ ((d & 7) << 3)];
        oacc[0][dt] = __builtin_amdgcn_mfma_f32_16x16x32_bf16(pf0, vf, oacc[0][dt], 0, 0, 0);
        oacc[1][dt] = __builtin_amdgcn_mfma_f32_16x16x32_bf16(pf1, vf, oacc[1][dt], 0, 0, 0);
      }
    }
    __builtin_amdgcn_s_setprio(0);
  }

  if (partial) {
    const int pid = pid_base(qt) + s;
#pragma unroll
    for (int hh = 0; hh < 2; hh++) {
      const int sub = (g * 2 + hp) * 2 + hh;
      uint2* dst = (uint2*)pO + (size_t)(pid * 32 + sub) * 2048;
#pragma unroll
      for (int dt = 0; dt < 8; dt++) {
        bf16 pk[4];
#pragma unroll
        for (int r = 0; r < 4; r++) pk[r] = tobf(oacc[hh][dt][r]);
        uint2 uu; __builtin_memcpy(&uu, pk, 8);
        dst[(wave * 8 + dt) * 64 + lane] = uu;
      }
      if (llo == 0) {
#pragma unroll
        for (int r = 0; r < 4; r++) {
          int row = wave * 16 + lhi * 4 + r;
          float* pm = pML + ((size_t)(pid * 32 + sub) * 64 + row) * 2;
          pm[0] = mrow[hh][r];
          pm[1] = lrow[hh][r];
        }
      }
    }
  } else {
#pragma unroll
    for (int hh = 0; hh < 2; hh++) {
      float inv[4];
#pragma unroll
      for (int r = 0; r < 4; r++) inv[r] = 1.f / lrow[hh][r];
      f32x4 o[8];
#pragma unroll
      for (int dt = 0; dt < 8; dt++)
#pragma unroll
        for (int r = 0; r < 4; r++) o[dt][r] = oacc[hh][dt][r] * inv[r];
      finalize_store(o, wave, lhi, llo, tid, h0 + hh, qt, tok0, g1t, lng, lnb, sK, aout);
    }
  }
}

// ---------------- combine ns partials (2..4) + LN + g1 gate ----------------
// 384 blocks; m values are in log2 domain (weights via exp2f, matching the split).
__global__ __launch_bounds__(256) void attn_combine_k(
    const bf16* __restrict__ pO, const float* __restrict__ pML,
    const float* __restrict__ g1t, const float* __restrict__ lng,
    const float* __restrict__ lnb, bf16* __restrict__ aout) {
  __shared__ bf16 stg[64 * 128];
  const int bid = blockIdx.x;
  const int g = bid & 7, j = bid >> 3;
  const int hp = j & 1, qtc = j >> 1;
  const int qt = 8 + qtc;
  const int ns = (qt < 16) ? 2 : (qt < 24) ? 3 : 4;
  const int p0id = pid_base(qt);
  const int b = g >> 2, kvh = g & 3, h0 = kvh * 4 + hp * 2;
  const int tid = threadIdx.x, wave = tid >> 6, lane = tid & 63;
  const int lhi = lane >> 4, llo = lane & 15;
  const size_t tok0 = (size_t)b * 2048;
#pragma unroll
  for (int hh = 0; hh < 2; hh++) {
    const int sub = (g * 2 + hp) * 2 + hh;
    float w[4][4], inv[4];
#pragma unroll
    for (int r = 0; r < 4; r++) {
      int row = wave * 16 + lhi * 4 + r;
      float m[4], l[4], ms = -1e30f;
#pragma unroll
      for (int sp = 0; sp < 4; sp++)
        if (sp < ns) {
          const float* q = pML + ((size_t)((p0id + sp) * 32 + sub) * 64 + row) * 2;
          m[sp] = q[0]; l[sp] = q[1];
          ms = fmaxf(ms, m[sp]);
        }
      float L = 0.f;
#pragma unroll
      for (int sp = 0; sp < 4; sp++)
        if (sp < ns) { w[sp][r] = exp2f(m[sp] - ms); L += w[sp][r] * l[sp]; }
      inv[r] = 1.f / L;
    }
    f32x4 o[8];
#pragma unroll
    for (int dt = 0; dt < 8; dt++) {
      f32x4 a = f32x4{0.f, 0.f, 0.f, 0.f};
#pragma unroll
      for (int sp = 0; sp < 4; sp++)
        if (sp < ns) {
          uint2 uu = ((const uint2*)pO + (size_t)((p0id + sp) * 32 + sub) * 2048)
                         [(wave * 8 + dt) * 64 + lane];
          bf16 pk[4]; __builtin_memcpy(pk, &uu, 8);
#pragma unroll
          for (int r = 0; r < 4; r++) a[r] += w[sp][r] * tof(pk[r]);
        }
#pragma unroll
      for (int r = 0; r < 4; r++) o[dt][r] = a[r] * inv[r];
    }
    finalize_store(o, wave, lhi, llo, tid, h0 + hh, qt, tok0, g1t, lng, lnb, stg, aout);
  }
}

// ---------------- launch ----------------
extern "C" void kernel_launch(void* const* d_in, const int* in_sizes, int n_in,
                              void* d_out, int out_size, void* d_ws, size_t ws_size,
                              hipStream_t stream) {
  (void)in_sizes; (void)n_in; (void)out_size; (void)ws_size;
  const float* X   = (const float*)d_in[0];
  const int*   pos = (const int*)d_in[1];
  const float* Wq  = (const float*)d_in[2];
  const float* Wk  = (const float*)d_in[3];
  const float* Wv  = (const float*)d_in[4];
  const float* Wo  = (const float*)d_in[5];
  const float* Wg1 = (const float*)d_in[6];
  const float* bg1 = (const float*)d_in[7];
  const float* Wg2 = (const float*)d_in[8];
  const float* bg2 = (const float*)d_in[9];
  const float* lng = (const float*)d_in[10];
  const float* lnb = (const float*)d_in[11];

  char* ws = (char*)d_ws;
  size_t off = 0;
  auto alloc = [&](size_t bytes) {
    void* p = ws + off;
    off += (bytes + 255) & ~(size_t)255;
    return p;
  };
  bf16*  WT   = (bf16*)alloc(3200ull * 2048 * 2);   // [Wq^T; Wk^T; Wv^T; Wg1^T; Wg2^T; pad]
  bf16*  WoT  = (bf16*)alloc(2048ull * 2048 * 2);
  bf16*  Xbf  = (bf16*)alloc(4096ull * 2048 * 2);
  bf16*  qkv  = (bf16*)alloc(4096ull * 3072 * 2);
  bf16*  attn = (bf16*)alloc(4096ull * 2048 * 2);
  float* cosT = (float*)alloc(2048ull * 64 * 4);
  float* sinT = (float*)alloc(2048ull * 64 * 4);
  float* g1t  = (float*)alloc(16ull * 4096 * 4);    // [head][token]
  float* g2t  = (float*)alloc(16ull * 4096 * 4);
  bf16*  pO   = (bf16*)alloc(80ull * 32 * 2048 * 8);  // [pid][sub] bf16x4-coalesced partials
  float* pML  = (float*)alloc(80ull * 32 * 64 * 2 * 4);

  // all prep in one launch: weight transposes (128B-segment writes), X cast,
  // rope tables, gate-weight transpose
  prep_all_k<<<5152, 256, 0, stream>>>(X, pos, Wq, Wk, Wv, Wo, Wg1, Wg2,
                                       WT, WoT, Xbf, cosT, sinT);

  // [qkv | g1t | g2t] = Xbf @ WT^T  (4096 x 3200), RoPE + Q log2-prescale fused
  gemm_qkv_k<<<800, 256, 0, stream>>>(Xbf, WT, qkv, g1t, g2t, bg1, bg2, cosT, sinT);
  attn_split_k<<<1280, 256, 0, stream>>>(qkv, g2t, g1t, lng, lnb, pO, pML, attn);
  attn_combine_k<<<384, 256, 0, stream>>>(pO, pML, g1t, lng, lnb, attn);
  // out = attn @ Wo  (4096 x 2048), fp32
  gemm_out_k<<<512, 256, 0, stream>>>(attn, WoT, (float*)d_out, 2048, 2048);
}

// Round 19
// 280.378 us; speedup vs baseline: 1.0288x; 1.0288x over previous
//
#include <hip/hip_runtime.h>
#include <hip/hip_bf16.h>
#include <stdint.h>
#include <string.h>

using bf16 = __hip_bfloat16;
typedef __attribute__((ext_vector_type(8))) short bf16x8;   // 8 bf16 (4 VGPRs) MFMA A/B frag
typedef __attribute__((ext_vector_type(4))) float f32x4;    // MFMA C/D frag

#define DEV static __device__ __forceinline__

DEV bf16 tobf(float f) { return __float2bfloat16(f); }
DEV float tof(bf16 h) { return __bfloat162float(h); }
DEV float fexp2(float x) { return __builtin_amdgcn_exp2f(x); }  // bare v_exp_f32 (args <= 0 here)

// async global->LDS, 16B per lane. LDS dest semantics: wave-uniform base + lane*16.
DEV void gload_lds16(const void* g, void* l) {
  __builtin_amdgcn_global_load_lds((__attribute__((address_space(1))) void*)g,
                                   (__attribute__((address_space(3))) void*)l,
                                   16, 0, 0);
}

// ---------------- fused prep kernel ----------------
// One flat grid, 5152 blocks x 256 threads:
//   t <  2560 : 64x64 transpose+cast tiles over {Wq,Wk,Wv,Wo} -> WT / WoT
//   t <  4608 : cast X fp32 -> bf16 (4 float4/thread)
//   t <  5120 : rope cos/sin tables (4 s-rows/block)
//   else      : Wg1/Wg2 transpose into WT rows 3072..3103
__global__ __launch_bounds__(256) void prep_all_k(
    const float* __restrict__ X, const int* __restrict__ pos,
    const float* __restrict__ Wq, const float* __restrict__ Wk,
    const float* __restrict__ Wv, const float* __restrict__ Wo,
    const float* __restrict__ Wg1, const float* __restrict__ Wg2,
    bf16* __restrict__ WT, bf16* __restrict__ WoT, bf16* __restrict__ Xbf,
    float* __restrict__ cosT, float* __restrict__ sinT) {
  __shared__ float tile[64][65];
  const int t = blockIdx.x, tid = threadIdx.x;
  if (t < 2560) {
    const float* src; bf16* dst; int N, kb, nb;
    if (t < 1024)      { src = Wq; dst = WT;                  N = 2048; kb = (t >> 5) << 6;          nb = (t & 31) << 6; }
    else if (t < 1280) { int l = t - 1024; src = Wk; dst = WT + 2048ull * 2048; N = 512; kb = (l >> 3) << 6; nb = (l & 7) << 6; }
    else if (t < 1536) { int l = t - 1280; src = Wv; dst = WT + 2560ull * 2048; N = 512; kb = (l >> 3) << 6; nb = (l & 7) << 6; }
    else               { int l = t - 1536; src = Wo; dst = WoT;                N = 2048; kb = (l >> 5) << 6; nb = (l & 31) << 6; }
    const int c = tid & 63, r0 = tid >> 6;
#pragma unroll
    for (int i = 0; i < 16; i++) {
      int r = i * 4 + r0;
      tile[r][c] = src[(size_t)(kb + r) * N + nb + c];
    }
    __syncthreads();
    const int q = tid & 7;
#pragma unroll
    for (int p = 0; p < 2; p++) {
      int n = p * 32 + (tid >> 3);
      bf16 pk[8];
#pragma unroll
      for (int j = 0; j < 8; j++) pk[j] = tobf(tile[q * 8 + j][n]);
      uint4 u; __builtin_memcpy(&u, pk, 16);
      *(uint4*)(dst + (size_t)(nb + n) * 2048 + kb + q * 8) = u;
    }
  } else if (t < 4608) {
    const int blk = t - 2560;
#pragma unroll
    for (int j = 0; j < 4; j++) {
      int idx = blk * 1024 + j * 256 + tid;
      float4 v = ((const float4*)X)[idx];
      bf16 p4[4] = {tobf(v.x), tobf(v.y), tobf(v.z), tobf(v.w)};
      uint2 p; __builtin_memcpy(&p, p4, 8);
      ((uint2*)Xbf)[idx] = p;
    }
  } else if (t < 5120) {
    const int blk = t - 4608;
    int s = blk * 4 + (tid >> 6), i = tid & 63;
    double inv = exp(-((double)(2 * i) / 128.0) * log(10000.0));
    float f = (float)pos[s] * (float)inv;
    cosT[s * 64 + i] = cosf(f);
    sinT[s * 64 + i] = sinf(f);
  } else {
    const int blk = t - 5120;
    int g = blk >> 4, r = blk & 15;
    const float* src = g ? Wg2 : Wg1;
    bf16* dst = WT + (size_t)(3072 + g * 16 + r) * 2048;
    for (int k = tid; k < 2048; k += 256) dst[k] = tobf(src[(size_t)k * 16 + r]);
  }
}

// ---------------- QKV+gates GEMM with fused RoPE: [qkv | g1t | g2t] = Xbf @ WT^T ----
// Q heads (bn<16) are additionally pre-scaled by 1/sqrt(128)*log2(e) so attention's
// QK^T lands directly in the log2 softmax domain (saves scale-mul + exp pre-mul there).
__global__ __launch_bounds__(256, 2) void gemm_qkv_k(
    const bf16* __restrict__ A, const bf16* __restrict__ Bt, bf16* __restrict__ qkv,
    float* __restrict__ g1t, float* __restrict__ g2t,
    const float* __restrict__ bg1, const float* __restrict__ bg2,
    const float* __restrict__ cosT, const float* __restrict__ sinT) {
  constexpr int BK = 32, K = 2048;
  __shared__ bf16 smem[16384];  // sA = smem[0..8191] (2 bufs), sB = smem[8192..16383]; ex = all
  const int tid = threadIdx.x, wave = tid >> 6, lane = tid & 63;
  const int lhi = lane >> 4, llo = lane & 15;
  const int wm = wave >> 1, wn = wave & 1;
  const int bid = blockIdx.x;
  const int swz = (bid & 7) * 100 + (bid >> 3);  // bijective: 800 = 8*100
  const int bm = swz & 31, bn = swz >> 5;        // bn in 0..24
  const bf16* Ag = A + (size_t)bm * 128 * K;
  const bf16* Bg = Bt + (size_t)bn * 128 * K;

  f32x4 acc[4][4];
#pragma unroll
  for (int m = 0; m < 4; m++)
#pragma unroll
    for (int n = 0; n < 4; n++) acc[m][n] = f32x4{0.f, 0.f, 0.f, 0.f};

  auto stage = [&](int buf, int kt) {
#pragma unroll
    for (int i = 0; i < 2; i++) {
      int c = i * 256 + tid, row = c >> 2, c8 = c & 3;
      gload_lds16(Ag + (size_t)row * K + kt * BK + c8 * 8, smem + buf * 4096 + c * 8);
    }
#pragma unroll
    for (int i = 0; i < 2; i++) {
      int c = i * 256 + tid, row = c >> 2, c8 = c & 3;
      gload_lds16(Bg + (size_t)row * K + kt * BK + c8 * 8, smem + 8192 + buf * 4096 + c * 8);
    }
  };

  const int NT = K / BK;
  stage(0, 0);
  for (int kt = 0; kt < NT; kt++) {
    __syncthreads();
    if (kt + 1 < NT) stage((kt + 1) & 1, kt + 1);
    const bf16* a_ = smem + (kt & 1) * 4096;
    const bf16* b_ = smem + 8192 + (kt & 1) * 4096;
    bf16x8 af[4], bfr[4];
#pragma unroll
    for (int m = 0; m < 4; m++)
      af[m] = *(const bf16x8*)&a_[(wm * 64 + m * 16 + llo) * BK + lhi * 8];
#pragma unroll
    for (int n = 0; n < 4; n++)
      bfr[n] = *(const bf16x8*)&b_[(wn * 64 + n * 16 + llo) * BK + lhi * 8];
#pragma unroll
    for (int m = 0; m < 4; m++)
#pragma unroll
      for (int n = 0; n < 4; n++)
        acc[m][n] = __builtin_amdgcn_mfma_f32_16x16x32_bf16(af[m], bfr[n], acc[m][n], 0, 0, 0);
  }

  if (bn < 24) {
    // stage full 128x128 tile as bf16 into LDS (over sA/sB)
    bf16* ex = smem;
    __syncthreads();  // all waves done reading sA/sB
#pragma unroll
    for (int m = 0; m < 4; m++)
#pragma unroll
      for (int n = 0; n < 4; n++) {
        int wrow = wm * 64 + m * 16 + lhi * 4;
        int wc = wn * 64 + n * 16 + llo;
#pragma unroll
        for (int r = 0; r < 4; r++) ex[(wrow + r) * 128 + wc] = tobf(acc[m][n][r]);
      }
    __syncthreads();
    if (bn < 20) {
      // RoPE: 128 rows x 8 lo-chunks (8 cols), 4 per thread.
      // Q heads: extra pre-scale by 1/sqrt(128)*log2(e) for log2-domain softmax.
      const float qs = (bn < 16) ? 0.12751651545f : 1.0f;
#pragma unroll
      for (int i = 0; i < 4; i++) {
        int c = i * 256 + tid, row = c >> 3, d0 = (c & 7) * 8;
        int token = bm * 128 + row, s = token & 2047;
        bf16x8 lo = *(const bf16x8*)&ex[row * 128 + d0];
        bf16x8 hi = *(const bf16x8*)&ex[row * 128 + d0 + 64];
        float4 ca = *(const float4*)(cosT + s * 64 + d0);
        float4 cb = *(const float4*)(cosT + s * 64 + d0 + 4);
        float4 sa = *(const float4*)(sinT + s * 64 + d0);
        float4 sb = *(const float4*)(sinT + s * 64 + d0 + 4);
        float cs[8] = {ca.x, ca.y, ca.z, ca.w, cb.x, cb.y, cb.z, cb.w};
        float sn[8] = {sa.x, sa.y, sa.z, sa.w, sb.x, sb.y, sb.z, sb.w};
        bf16x8 olo, ohi;
#pragma unroll
        for (int jj = 0; jj < 8; jj++) {
          float a = tof(((const bf16*)&lo)[jj]), b2 = tof(((const bf16*)&hi)[jj]);
          ((bf16*)&olo)[jj] = tobf((a * cs[jj] - b2 * sn[jj]) * qs);
          ((bf16*)&ohi)[jj] = tobf((b2 * cs[jj] + a * sn[jj]) * qs);
        }
        bf16* dst = qkv + (size_t)token * 3072 + bn * 128 + d0;
        *(uint4*)dst = *(const uint4*)&olo;
        *(uint4*)(dst + 64) = *(const uint4*)&ohi;
      }
    } else {
      // V: plain coalesced copy-out, 8 uint4 per thread
#pragma unroll
      for (int i = 0; i < 8; i++) {
        int c = i * 256 + tid, row = c >> 4, ch = c & 15;
        int token = bm * 128 + row;
        *(uint4*)(qkv + (size_t)token * 3072 + bn * 128 + ch * 8) =
            *(const uint4*)&ex[row * 128 + ch * 8];
      }
    }
  } else {
    const int r0 = bm * 128 + wm * 64, c0 = bn * 128 + wn * 64;
#pragma unroll
    for (int m = 0; m < 4; m++)
#pragma unroll
      for (int n = 0; n < 4; n++) {
        int col = c0 + n * 16 + llo;
#pragma unroll
        for (int r = 0; r < 4; r++) {
          int row = r0 + m * 16 + lhi * 4 + r;
          if (col >= 3072 && col < 3104) {
            int idx = col - 3072, hh = idx & 15;
            float b = (idx < 16) ? bg1[hh] : bg2[hh];
            float v = 1.f / (1.f + __expf(-(acc[m][n][r] + b)));
            ((idx < 16) ? g1t : g2t)[(size_t)hh * 4096 + row] = v;
          }
        }
      }
  }
}

// ---------------- output GEMM: C = A(4096xK) * Bt(2048xK)^T, fp32 out ----------------
__global__ __launch_bounds__(256, 2) void gemm_out_k(
    const bf16* __restrict__ A, const bf16* __restrict__ Bt, float* __restrict__ C,
    int N, int K) {
  constexpr int BK = 32;
  __shared__ bf16 sA[2][128 * BK];
  __shared__ bf16 sB[2][128 * BK];
  const int tid = threadIdx.x, wave = tid >> 6, lane = tid & 63;
  const int lhi = lane >> 4, llo = lane & 15;
  const int wm = wave >> 1, wn = wave & 1;
  const int bid = blockIdx.x;
  const int swz = (bid & 7) * 64 + (bid >> 3);  // bijective: 512 = 8*64
  const int bm = swz & 31, bn = swz >> 5;       // bn in 0..15
  const bf16* Ag = A + (size_t)bm * 128 * K;
  const bf16* Bg = Bt + (size_t)bn * 128 * K;

  f32x4 acc[4][4];
#pragma unroll
  for (int m = 0; m < 4; m++)
#pragma unroll
    for (int n = 0; n < 4; n++) acc[m][n] = f32x4{0.f, 0.f, 0.f, 0.f};

  auto stage = [&](int buf, int kt) {
#pragma unroll
    for (int i = 0; i < 2; i++) {
      int c = i * 256 + tid, row = c >> 2, c8 = c & 3;
      gload_lds16(Ag + (size_t)row * K + kt * BK + c8 * 8, &sA[buf][c * 8]);
    }
#pragma unroll
    for (int i = 0; i < 2; i++) {
      int c = i * 256 + tid, row = c >> 2, c8 = c & 3;
      gload_lds16(Bg + (size_t)row * K + kt * BK + c8 * 8, &sB[buf][c * 8]);
    }
  };

  const int NT = K / BK;
  stage(0, 0);
  for (int kt = 0; kt < NT; kt++) {
    __syncthreads();
    if (kt + 1 < NT) stage((kt + 1) & 1, kt + 1);
    const bf16* a_ = sA[kt & 1];
    const bf16* b_ = sB[kt & 1];
    bf16x8 af[4], bfr[4];
#pragma unroll
    for (int m = 0; m < 4; m++)
      af[m] = *(const bf16x8*)&a_[(wm * 64 + m * 16 + llo) * BK + lhi * 8];
#pragma unroll
    for (int n = 0; n < 4; n++)
      bfr[n] = *(const bf16x8*)&b_[(wn * 64 + n * 16 + llo) * BK + lhi * 8];
#pragma unroll
    for (int m = 0; m < 4; m++)
#pragma unroll
      for (int n = 0; n < 4; n++)
        acc[m][n] = __builtin_amdgcn_mfma_f32_16x16x32_bf16(af[m], bfr[n], acc[m][n], 0, 0, 0);
  }

  const int r0 = bm * 128 + wm * 64, c0 = bn * 128 + wn * 64;
#pragma unroll
  for (int m = 0; m < 4; m++)
#pragma unroll
    for (int n = 0; n < 4; n++)
#pragma unroll
      for (int r = 0; r < 4; r++)
        C[(size_t)(r0 + m * 16 + lhi * 4 + r) * N + (c0 + n * 16 + llo)] = acc[m][n][r];
}

// ---------------- shared attention epilogue: LN + g1 gate + coalesced store ----------------
DEV void finalize_store(const f32x4 (&o)[8], int wave, int lhi, int llo, int tid,
                        int h, int qt, size_t tok0,
                        const float* __restrict__ g1t, const float* __restrict__ lng,
                        const float* __restrict__ lnb, bf16* stg, bf16* __restrict__ aout) {
  float sum[4] = {0, 0, 0, 0}, sq[4] = {0, 0, 0, 0};
#pragma unroll
  for (int dt = 0; dt < 8; dt++)
#pragma unroll
    for (int r = 0; r < 4; r++) {
      float v = o[dt][r];
      sum[r] += v;
      sq[r] += v * v;
    }
  float mu[4], rstd[4];
#pragma unroll
  for (int r = 0; r < 4; r++) {
    float s1 = sum[r], s2 = sq[r];
    s1 += __shfl_xor(s1, 1); s1 += __shfl_xor(s1, 2); s1 += __shfl_xor(s1, 4); s1 += __shfl_xor(s1, 8);
    s2 += __shfl_xor(s2, 1); s2 += __shfl_xor(s2, 2); s2 += __shfl_xor(s2, 4); s2 += __shfl_xor(s2, 8);
    float m_ = s1 * (1.f / 128.f);
    float var = s2 * (1.f / 128.f) - m_ * m_;
    mu[r] = m_;
    rstd[r] = rsqrtf(var + 1e-5f);
  }
  __syncthreads();  // prior users of stg done
#pragma unroll
  for (int r = 0; r < 4; r++) {
    int lrow = wave * 16 + lhi * 4 + r;
    float gg = g1t[(size_t)h * 4096 + tok0 + qt * 64 + lrow];
#pragma unroll
    for (int dt = 0; dt < 8; dt++) {
      int d = dt * 16 + llo;
      float v = (o[dt][r] - mu[r]) * rstd[r] * lng[d] + lnb[d];
      stg[lrow * 128 + d] = tobf(v * gg);
    }
  }
  __syncthreads();
#pragma unroll
  for (int i = 0; i < 4; i++) {
    int c = i * 256 + tid, lr = c >> 4, c8 = c & 15;
    *(uint4*)(aout + (tok0 + qt * 64 + lr) * 2048 + h * 128 + c8 * 8) =
        *(const uint4*)&stg[lr * 128 + c8 * 8];
  }
}

// cumulative split count before qt (8-tile chunks): pid = pid_base(qt) + s, 80 total
DEV int pid_base(int qt) {
  return qt < 8 ? qt : qt < 16 ? 2 * qt - 8 : qt < 24 ? 3 * qt - 24 : 4 * qt - 48;
}

// LPT-ordered (qt,s) unit table, encoded qt*4+s. Full 8-tile chunks first, then
// remainder chunks by length descending (7..1).
__device__ const unsigned char UNIT_TAB[80] = {
  124,125,126,127,                          // qt31 x4 (len8)
  120,121,122, 116,117,118, 112,113,114,    // qt30..28 (len8)
  108,109,110, 104,105,106, 100,101,102,    // qt27..25
   96, 97, 98,  92, 93, 94,                 // qt24, qt23
   88, 89,  84, 85,  80, 81,  76, 77,       // qt22..19 (len8)
   72, 73,  68, 69,  64, 65,  60, 61,       // qt18..15
   56, 52, 48, 44, 40, 36, 32, 28,          // qt14..7 (len8, single/first)
  123, 90, 57, 24,                          // len7: (30,3)(22,2)(14,1)(6,0)
  119, 86, 53, 20,                          // len6
  115, 82, 49, 16,                          // len5
  111, 78, 45, 12,                          // len4
  107, 74, 41,  8,                          // len3
  103, 70, 37,  4,                          // len2
   99, 66, 33,  0                           // len1
};

// ---------------- split-K causal GQA attention: 2 q-heads, 8-tile LPT units ----------------
// R9 body + T5 s_setprio (R15) + bf16 partials (R17). Softmax in log2 domain with RAW
// v_exp_f32 (__builtin_amdgcn_exp2f): args are <= 0 and either > -30 (real scores) or
// -1e30 (masked -> underflow to 0), so libm exp2f's denormal fixup (the R18 regression:
// VALUBusy 31->35%) is provably unnecessary. Q carries 1/sqrt(128)*log2(e).
__global__ __launch_bounds__(256, 2) void attn_split_k(
    const bf16* __restrict__ qkv, const float* __restrict__ g2t,
    const float* __restrict__ g1t, const float* __restrict__ lng,
    const float* __restrict__ lnb,
    bf16* __restrict__ pO, float* __restrict__ pML, bf16* __restrict__ aout) {
  constexpr int S = 2048, LD = 3072;
  const int bid = blockIdx.x;
  const int g = bid & 7, j = bid >> 3;
  const int hp = j & 1, u = j >> 1;
  const int e = UNIT_TAB[u];
  const int qt = e >> 2, s = e & 3;
  const int k0 = s * 8, k1 = min(s * 8 + 8, qt + 1);
  const bool partial = (qt >= 8);

  const int b = g >> 2, kvh = g & 3, h0 = kvh * 4 + hp * 2;
  const int tid = threadIdx.x, wave = tid >> 6, lane = tid & 63;
  const int lhi = lane >> 4, llo = lane & 15;
  const size_t tok0 = (size_t)b * S;

  __shared__ bf16 sK[64 * 128];      // [kv][d], XOR-swizzled ((row&7)<<3 on element idx)
  __shared__ bf16 sV[128 * 64];      // [d][kv] transposed, XOR-swizzled ((d&7)<<3)
  __shared__ bf16 sP[4][2][16][72];  // per-wave, per-head P tile, padded

  const int qrow0 = qt * 64 + wave * 16;

  bf16x8 qf[2][4];
#pragma unroll
  for (int hh = 0; hh < 2; hh++) {
    const bf16* qg = qkv + (tok0 + qrow0 + llo) * LD + (h0 + hh) * 128;
#pragma unroll
    for (int dc = 0; dc < 4; dc++) qf[hh][dc] = *(const bf16x8*)(qg + dc * 32 + lhi * 8);
  }

  f32x4 oacc[2][8];
#pragma unroll
  for (int hh = 0; hh < 2; hh++)
#pragma unroll
    for (int i = 0; i < 8; i++) oacc[hh][i] = f32x4{0.f, 0.f, 0.f, 0.f};
  float mrow[2][4], lrow[2][4];
#pragma unroll
  for (int hh = 0; hh < 2; hh++)
#pragma unroll
    for (int r = 0; r < 4; r++) { mrow[hh][r] = -1e30f; lrow[hh][r] = 0.f; }

  uint4 kreg[4];
  bf16x8 vreg[4];
  float gvreg[2];
  const int vdg = tid >> 4;   // d-group: 8 d elems
  const int vkg = tid & 15;   // kv-group: 4 kv rows

  auto issue_loads = [&](int kt) {
#pragma unroll
    for (int i = 0; i < 4; i++) {
      int c = i * 256 + tid, row = c >> 4, c8 = c & 15;
      kreg[i] = *(const uint4*)(qkv + (tok0 + kt * 64 + row) * LD + 2048 + kvh * 128 + c8 * 8);
    }
#pragma unroll
    for (int r = 0; r < 4; r++)
      vreg[r] = *(const bf16x8*)(qkv + (tok0 + kt * 64 + vkg * 4 + r) * LD + 2560 +
                                 kvh * 128 + vdg * 8);
#pragma unroll
    for (int hh = 0; hh < 2; hh++)
      gvreg[hh] = g2t[(size_t)(h0 + hh) * 4096 + tok0 + kt * 64 + lane];
  };

  auto write_lds = [&]() {
#pragma unroll
    for (int i = 0; i < 4; i++) {
      int c = i * 256 + tid, row = c >> 4, c8 = c & 15;
      int eidx = (row * 128 + c8 * 8) ^ ((row & 7) << 3);
      *(uint4*)&sK[eidx] = kreg[i];
    }
#pragma unroll
    for (int e2 = 0; e2 < 8; e2++) {
      int d = vdg * 8 + e2;          // d & 7 == e2
      uint32_t lo = (uint32_t)(unsigned short)vreg[0][e2] |
                    ((uint32_t)(unsigned short)vreg[1][e2] << 16);
      uint32_t hi = (uint32_t)(unsigned short)vreg[2][e2] |
                    ((uint32_t)(unsigned short)vreg[3][e2] << 16);
      int eidx = (d * 64 + vkg * 4) ^ (e2 << 3);
      uint2 pk; pk.x = lo; pk.y = hi;
      *(uint2*)&sV[eidx] = pk;
    }
  };

  issue_loads(k0);
  for (int kt = k0; kt < k1; kt++) {
    __syncthreads();  // previous tile's LDS reads complete before overwrite
    write_lds();      // vmcnt wait lands here (data long arrived)
    float gv0 = gvreg[0], gv1 = gvreg[1];
    if (kt + 1 < k1) issue_loads(kt + 1);  // registers only; in flight across barrier+compute
    __syncthreads();  // LDS writes visible

    const bool diag = (kt == qt);
#pragma unroll
    for (int hh = 0; hh < 2; hh++) {
      // ---- QK^T (T5: raise wave priority through the MFMA cluster) ----
      f32x4 sc[4];
      __builtin_amdgcn_s_setprio(1);
#pragma unroll
      for (int ct = 0; ct < 4; ct++) {
        f32x4 acc = f32x4{0.f, 0.f, 0.f, 0.f};
#pragma unroll
        for (int dc = 0; dc < 4; dc++) {
          int row = ct * 16 + llo;
          bf16x8 kf = *(const bf16x8*)&sK[(row * 128 + dc * 32 + lhi * 8) ^ ((row & 7) << 3)];
          acc = __builtin_amdgcn_mfma_f32_16x16x32_bf16(qf[hh][dc], kf, acc, 0, 0, 0);
        }
        sc[ct] = acc;
      }
      __builtin_amdgcn_s_setprio(0);
      // ---- causal mask + online softmax, log2 domain (exact defer-max) ----
      float pm[4] = {-1e30f, -1e30f, -1e30f, -1e30f};
#pragma unroll
      for (int ct = 0; ct < 4; ct++) {
        int kv = kt * 64 + ct * 16 + llo;
#pragma unroll
        for (int r = 0; r < 4; r++) {
          float s_ = sc[ct][r];
          if (diag && kv > qrow0 + lhi * 4 + r) s_ = -1e30f;
          sc[ct][r] = s_;
          pm[r] = fmaxf(pm[r], s_);
        }
      }
#pragma unroll
      for (int r = 0; r < 4; r++) {
        float v = pm[r];
        v = fmaxf(v, __shfl_xor(v, 1));
        v = fmaxf(v, __shfl_xor(v, 2));
        v = fmaxf(v, __shfl_xor(v, 4));
        v = fmaxf(v, __shfl_xor(v, 8));
        pm[r] = v;
      }
      int need = 0;
#pragma unroll
      for (int r = 0; r < 4; r++) need |= (pm[r] > mrow[hh][r]) ? 1 : 0;
      if (__any(need)) {
#pragma unroll
        for (int r = 0; r < 4; r++) {
          float mnew = fmaxf(mrow[hh][r], pm[r]);
          float al = fexp2(mrow[hh][r] - mnew);
          mrow[hh][r] = mnew;
          lrow[hh][r] *= al;
#pragma unroll
          for (int i = 0; i < 8; i++) oacc[hh][i][r] *= al;
        }
      }
      float gv = hh ? gv1 : gv0;
      float g2v[4];
#pragma unroll
      for (int ct = 0; ct < 4; ct++) g2v[ct] = __shfl(gv, ct * 16 + llo);
      float rs[4] = {0.f, 0.f, 0.f, 0.f};
#pragma unroll
      for (int ct = 0; ct < 4; ct++) {
#pragma unroll
        for (int r = 0; r < 4; r++) {
          float p = fexp2(sc[ct][r] - mrow[hh][r]);
          rs[r] += p;  // softmax denom uses UNGATED p
          sP[wave][hh][lhi * 4 + r][ct * 16 + llo] = tobf(p * g2v[ct]);
        }
      }
#pragma unroll
      for (int r = 0; r < 4; r++) {
        float v = rs[r];
        v += __shfl_xor(v, 1); v += __shfl_xor(v, 2); v += __shfl_xor(v, 4); v += __shfl_xor(v, 8);
        lrow[hh][r] += v;
      }
    }
    // ---- PV: both heads share each V fragment (T5 around MFMA cluster) ----
    __builtin_amdgcn_s_setprio(1);
#pragma unroll
    for (int kc = 0; kc < 2; kc++) {
      bf16x8 pf0 = *(const bf16x8*)&sP[wave][0][llo][kc * 32 + lhi * 8];
      bf16x8 pf1 = *(const bf16x8*)&sP[wave][1][llo][kc * 32 + lhi * 8];
#pragma unroll
      for (int dt = 0; dt < 8; dt++) {
        int d = dt * 16 + llo;
        bf16x8 vf = *(const bf16x8*)&sV[(d * 64 + kc * 32 + lhi * 8) ^ ((d & 7) << 3)];
        oacc[0][dt] = __builtin_amdgcn_mfma_f32_16x16x32_bf16(pf0, vf, oacc[0][dt], 0, 0, 0);
        oacc[1][dt] = __builtin_amdgcn_mfma_f32_16x16x32_bf16(pf1, vf, oacc[1][dt], 0, 0, 0);
      }
    }
    __builtin_amdgcn_s_setprio(0);
  }

  if (partial) {
    const int pid = pid_base(qt) + s;
#pragma unroll
    for (int hh = 0; hh < 2; hh++) {
      const int sub = (g * 2 + hp) * 2 + hh;
      uint2* dst = (uint2*)pO + (size_t)(pid * 32 + sub) * 2048;
#pragma unroll
      for (int dt = 0; dt < 8; dt++) {
        bf16 pk[4];
#pragma unroll
        for (int r = 0; r < 4; r++) pk[r] = tobf(oacc[hh][dt][r]);
        uint2 uu; __builtin_memcpy(&uu, pk, 8);
        dst[(wave * 8 + dt) * 64 + lane] = uu;
      }
      if (llo == 0) {
#pragma unroll
        for (int r = 0; r < 4; r++) {
          int row = wave * 16 + lhi * 4 + r;
          float* pm = pML + ((size_t)(pid * 32 + sub) * 64 + row) * 2;
          pm[0] = mrow[hh][r];
          pm[1] = lrow[hh][r];
        }
      }
    }
  } else {
#pragma unroll
    for (int hh = 0; hh < 2; hh++) {
      float inv[4];
#pragma unroll
      for (int r = 0; r < 4; r++) inv[r] = 1.f / lrow[hh][r];
      f32x4 o[8];
#pragma unroll
      for (int dt = 0; dt < 8; dt++)
#pragma unroll
        for (int r = 0; r < 4; r++) o[dt][r] = oacc[hh][dt][r] * inv[r];
      finalize_store(o, wave, lhi, llo, tid, h0 + hh, qt, tok0, g1t, lng, lnb, sK, aout);
    }
  }
}

// ---------------- combine ns partials (2..4) + LN + g1 gate ----------------
// 384 blocks; m values are in log2 domain (weights via raw v_exp_f32, matching split).
__global__ __launch_bounds__(256) void attn_combine_k(
    const bf16* __restrict__ pO, const float* __restrict__ pML,
    const float* __restrict__ g1t, const float* __restrict__ lng,
    const float* __restrict__ lnb, bf16* __restrict__ aout) {
  __shared__ bf16 stg[64 * 128];
  const int bid = blockIdx.x;
  const int g = bid & 7, j = bid >> 3;
  const int hp = j & 1, qtc = j >> 1;
  const int qt = 8 + qtc;
  const int ns = (qt < 16) ? 2 : (qt < 24) ? 3 : 4;
  const int p0id = pid_base(qt);
  const int b = g >> 2, kvh = g & 3, h0 = kvh * 4 + hp * 2;
  const int tid = threadIdx.x, wave = tid >> 6, lane = tid & 63;
  const int lhi = lane >> 4, llo = lane & 15;
  const size_t tok0 = (size_t)b * 2048;
#pragma unroll
  for (int hh = 0; hh < 2; hh++) {
    const int sub = (g * 2 + hp) * 2 + hh;
    float w[4][4], inv[4];
#pragma unroll
    for (int r = 0; r < 4; r++) {
      int row = wave * 16 + lhi * 4 + r;
      float m[4], l[4], ms = -1e30f;
#pragma unroll
      for (int sp = 0; sp < 4; sp++)
        if (sp < ns) {
          const float* q = pML + ((size_t)((p0id + sp) * 32 + sub) * 64 + row) * 2;
          m[sp] = q[0]; l[sp] = q[1];
          ms = fmaxf(ms, m[sp]);
        }
      float L = 0.f;
#pragma unroll
      for (int sp = 0; sp < 4; sp++)
        if (sp < ns) { w[sp][r] = fexp2(m[sp] - ms); L += w[sp][r] * l[sp]; }
      inv[r] = 1.f / L;
    }
    f32x4 o[8];
#pragma unroll
    for (int dt = 0; dt < 8; dt++) {
      f32x4 a = f32x4{0.f, 0.f, 0.f, 0.f};
#pragma unroll
      for (int sp = 0; sp < 4; sp++)
        if (sp < ns) {
          uint2 uu = ((const uint2*)pO + (size_t)((p0id + sp) * 32 + sub) * 2048)
                         [(wave * 8 + dt) * 64 + lane];
          bf16 pk[4]; __builtin_memcpy(pk, &uu, 8);
#pragma unroll
          for (int r = 0; r < 4; r++) a[r] += w[sp][r] * tof(pk[r]);
        }
#pragma unroll
      for (int r = 0; r < 4; r++) o[dt][r] = a[r] * inv[r];
    }
    finalize_store(o, wave, lhi, llo, tid, h0 + hh, qt, tok0, g1t, lng, lnb, stg, aout);
  }
}

// ---------------- launch ----------------
extern "C" void kernel_launch(void* const* d_in, const int* in_sizes, int n_in,
                              void* d_out, int out_size, void* d_ws, size_t ws_size,
                              hipStream_t stream) {
  (void)in_sizes; (void)n_in; (void)out_size; (void)ws_size;
  const float* X   = (const float*)d_in[0];
  const int*   pos = (const int*)d_in[1];
  const float* Wq  = (const float*)d_in[2];
  const float* Wk  = (const float*)d_in[3];
  const float* Wv  = (const float*)d_in[4];
  const float* Wo  = (const float*)d_in[5];
  const float* Wg1 = (const float*)d_in[6];
  const float* bg1 = (const float*)d_in[7];
  const float* Wg2 = (const float*)d_in[8];
  const float* bg2 = (const float*)d_in[9];
  const float* lng = (const float*)d_in[10];
  const float* lnb = (const float*)d_in[11];

  char* ws = (char*)d_ws;
  size_t off = 0;
  auto alloc = [&](size_t bytes) {
    void* p = ws + off;
    off += (bytes + 255) & ~(size_t)255;
    return p;
  };
  bf16*  WT   = (bf16*)alloc(3200ull * 2048 * 2);   // [Wq^T; Wk^T; Wv^T; Wg1^T; Wg2^T; pad]
  bf16*  WoT  = (bf16*)alloc(2048ull * 2048 * 2);
  bf16*  Xbf  = (bf16*)alloc(4096ull * 2048 * 2);
  bf16*  qkv  = (bf16*)alloc(4096ull * 3072 * 2);
  bf16*  attn = (bf16*)alloc(4096ull * 2048 * 2);
  float* cosT = (float*)alloc(2048ull * 64 * 4);
  float* sinT = (float*)alloc(2048ull * 64 * 4);
  float* g1t  = (float*)alloc(16ull * 4096 * 4);    // [head][token]
  float* g2t  = (float*)alloc(16ull * 4096 * 4);
  bf16*  pO   = (bf16*)alloc(80ull * 32 * 2048 * 8);  // [pid][sub] bf16x4-coalesced partials
  float* pML  = (float*)alloc(80ull * 32 * 64 * 2 * 4);

  // all prep in one launch: weight transposes (128B-segment writes), X cast,
  // rope tables, gate-weight transpose
  prep_all_k<<<5152, 256, 0, stream>>>(X, pos, Wq, Wk, Wv, Wo, Wg1, Wg2,
                                       WT, WoT, Xbf, cosT, sinT);

  // [qkv | g1t | g2t] = Xbf @ WT^T  (4096 x 3200), RoPE + Q log2-prescale fused
  gemm_qkv_k<<<800, 256, 0, stream>>>(Xbf, WT, qkv, g1t, g2t, bg1, bg2, cosT, sinT);
  attn_split_k<<<1280, 256, 0, stream>>>(qkv, g2t, g1t, lng, lnb, pO, pML, attn);
  attn_combine_k<<<384, 256, 0, stream>>>(pO, pML, g1t, lng, lnb, attn);
  // out = attn @ Wo  (4096 x 2048), fp32
  gemm_out_k<<<512, 256, 0, stream>>>(attn, WoT, (float*)d_out, 2048, 2048);
}

// Round 20
// 276.856 us; speedup vs baseline: 1.0418x; 1.0127x over previous
//
#include <hip/hip_runtime.h>
#include <hip/hip_bf16.h>
#include <stdint.h>
#include <string.h>

using bf16 = __hip_bfloat16;
typedef __attribute__((ext_vector_type(8))) short bf16x8;   // 8 bf16 (4 VGPRs) MFMA A/B frag
typedef __attribute__((ext_vector_type(4))) float f32x4;    // MFMA C/D frag

#define DEV static __device__ __forceinline__

DEV bf16 tobf(float f) { return __float2bfloat16(f); }
DEV float tof(bf16 h) { return __bfloat162float(h); }
DEV float fexp2(float x) { return __builtin_amdgcn_exp2f(x); }  // bare v_exp_f32 (args <= 0 here)

// async global->LDS, 16B per lane. LDS dest semantics: wave-uniform base + lane*16.
DEV void gload_lds16(const void* g, void* l) {
  __builtin_amdgcn_global_load_lds((__attribute__((address_space(1))) void*)g,
                                   (__attribute__((address_space(3))) void*)l,
                                   16, 0, 0);
}

// ---------------- fused prep kernel ----------------
// One flat grid, 5152 blocks x 256 threads:
//   t <  2560 : 64x64 transpose+cast tiles over {Wq,Wk,Wv,Wo} -> WT / WoT
//   t <  4608 : cast X fp32 -> bf16 (4 float4/thread)
//   t <  5120 : rope cos/sin tables (4 s-rows/block)
//   else      : Wg1/Wg2 transpose into WT rows 3072..3103
__global__ __launch_bounds__(256) void prep_all_k(
    const float* __restrict__ X, const int* __restrict__ pos,
    const float* __restrict__ Wq, const float* __restrict__ Wk,
    const float* __restrict__ Wv, const float* __restrict__ Wo,
    const float* __restrict__ Wg1, const float* __restrict__ Wg2,
    bf16* __restrict__ WT, bf16* __restrict__ WoT, bf16* __restrict__ Xbf,
    float* __restrict__ cosT, float* __restrict__ sinT) {
  __shared__ float tile[64][65];
  const int t = blockIdx.x, tid = threadIdx.x;
  if (t < 2560) {
    const float* src; bf16* dst; int N, kb, nb;
    if (t < 1024)      { src = Wq; dst = WT;                  N = 2048; kb = (t >> 5) << 6;          nb = (t & 31) << 6; }
    else if (t < 1280) { int l = t - 1024; src = Wk; dst = WT + 2048ull * 2048; N = 512; kb = (l >> 3) << 6; nb = (l & 7) << 6; }
    else if (t < 1536) { int l = t - 1280; src = Wv; dst = WT + 2560ull * 2048; N = 512; kb = (l >> 3) << 6; nb = (l & 7) << 6; }
    else               { int l = t - 1536; src = Wo; dst = WoT;                N = 2048; kb = (l >> 5) << 6; nb = (l & 31) << 6; }
    const int c = tid & 63, r0 = tid >> 6;
#pragma unroll
    for (int i = 0; i < 16; i++) {
      int r = i * 4 + r0;
      tile[r][c] = src[(size_t)(kb + r) * N + nb + c];
    }
    __syncthreads();
    const int q = tid & 7;
#pragma unroll
    for (int p = 0; p < 2; p++) {
      int n = p * 32 + (tid >> 3);
      bf16 pk[8];
#pragma unroll
      for (int j = 0; j < 8; j++) pk[j] = tobf(tile[q * 8 + j][n]);
      uint4 u; __builtin_memcpy(&u, pk, 16);
      *(uint4*)(dst + (size_t)(nb + n) * 2048 + kb + q * 8) = u;
    }
  } else if (t < 4608) {
    const int blk = t - 2560;
#pragma unroll
    for (int j = 0; j < 4; j++) {
      int idx = blk * 1024 + j * 256 + tid;
      float4 v = ((const float4*)X)[idx];
      bf16 p4[4] = {tobf(v.x), tobf(v.y), tobf(v.z), tobf(v.w)};
      uint2 p; __builtin_memcpy(&p, p4, 8);
      ((uint2*)Xbf)[idx] = p;
    }
  } else if (t < 5120) {
    const int blk = t - 4608;
    int s = blk * 4 + (tid >> 6), i = tid & 63;
    double inv = exp(-((double)(2 * i) / 128.0) * log(10000.0));
    float f = (float)pos[s] * (float)inv;
    cosT[s * 64 + i] = cosf(f);
    sinT[s * 64 + i] = sinf(f);
  } else {
    const int blk = t - 5120;
    int g = blk >> 4, r = blk & 15;
    const float* src = g ? Wg2 : Wg1;
    bf16* dst = WT + (size_t)(3072 + g * 16 + r) * 2048;
    for (int k = tid; k < 2048; k += 256) dst[k] = tobf(src[(size_t)k * 16 + r]);
  }
}

// ---------------- QKV+gates GEMM with fused RoPE: [qkv | g1t | g2t] = Xbf @ WT^T ----
// Q heads (bn<16) are additionally pre-scaled by 1/sqrt(128)*log2(e) so attention's
// QK^T lands directly in the log2 softmax domain (saves scale-mul + exp pre-mul there).
__global__ __launch_bounds__(256, 2) void gemm_qkv_k(
    const bf16* __restrict__ A, const bf16* __restrict__ Bt, bf16* __restrict__ qkv,
    float* __restrict__ g1t, float* __restrict__ g2t,
    const float* __restrict__ bg1, const float* __restrict__ bg2,
    const float* __restrict__ cosT, const float* __restrict__ sinT) {
  constexpr int BK = 32, K = 2048;
  __shared__ bf16 smem[16384];  // sA = smem[0..8191] (2 bufs), sB = smem[8192..16383]; ex = all
  const int tid = threadIdx.x, wave = tid >> 6, lane = tid & 63;
  const int lhi = lane >> 4, llo = lane & 15;
  const int wm = wave >> 1, wn = wave & 1;
  const int bid = blockIdx.x;
  const int swz = (bid & 7) * 100 + (bid >> 3);  // bijective: 800 = 8*100
  const int bm = swz & 31, bn = swz >> 5;        // bn in 0..24
  const bf16* Ag = A + (size_t)bm * 128 * K;
  const bf16* Bg = Bt + (size_t)bn * 128 * K;

  f32x4 acc[4][4];
#pragma unroll
  for (int m = 0; m < 4; m++)
#pragma unroll
    for (int n = 0; n < 4; n++) acc[m][n] = f32x4{0.f, 0.f, 0.f, 0.f};

  auto stage = [&](int buf, int kt) {
#pragma unroll
    for (int i = 0; i < 2; i++) {
      int c = i * 256 + tid, row = c >> 2, c8 = c & 3;
      gload_lds16(Ag + (size_t)row * K + kt * BK + c8 * 8, smem + buf * 4096 + c * 8);
    }
#pragma unroll
    for (int i = 0; i < 2; i++) {
      int c = i * 256 + tid, row = c >> 2, c8 = c & 3;
      gload_lds16(Bg + (size_t)row * K + kt * BK + c8 * 8, smem + 8192 + buf * 4096 + c * 8);
    }
  };

  const int NT = K / BK;
  stage(0, 0);
  for (int kt = 0; kt < NT; kt++) {
    __syncthreads();
    if (kt + 1 < NT) stage((kt + 1) & 1, kt + 1);
    const bf16* a_ = smem + (kt & 1) * 4096;
    const bf16* b_ = smem + 8192 + (kt & 1) * 4096;
    bf16x8 af[4], bfr[4];
#pragma unroll
    for (int m = 0; m < 4; m++)
      af[m] = *(const bf16x8*)&a_[(wm * 64 + m * 16 + llo) * BK + lhi * 8];
#pragma unroll
    for (int n = 0; n < 4; n++)
      bfr[n] = *(const bf16x8*)&b_[(wn * 64 + n * 16 + llo) * BK + lhi * 8];
#pragma unroll
    for (int m = 0; m < 4; m++)
#pragma unroll
      for (int n = 0; n < 4; n++)
        acc[m][n] = __builtin_amdgcn_mfma_f32_16x16x32_bf16(af[m], bfr[n], acc[m][n], 0, 0, 0);
  }

  if (bn < 24) {
    // stage full 128x128 tile as bf16 into LDS (over sA/sB)
    bf16* ex = smem;
    __syncthreads();  // all waves done reading sA/sB
#pragma unroll
    for (int m = 0; m < 4; m++)
#pragma unroll
      for (int n = 0; n < 4; n++) {
        int wrow = wm * 64 + m * 16 + lhi * 4;
        int wc = wn * 64 + n * 16 + llo;
#pragma unroll
        for (int r = 0; r < 4; r++) ex[(wrow + r) * 128 + wc] = tobf(acc[m][n][r]);
      }
    __syncthreads();
    if (bn < 20) {
      // RoPE: 128 rows x 8 lo-chunks (8 cols), 4 per thread.
      // Q heads: extra pre-scale by 1/sqrt(128)*log2(e) for log2-domain softmax.
      const float qs = (bn < 16) ? 0.12751651545f : 1.0f;
#pragma unroll
      for (int i = 0; i < 4; i++) {
        int c = i * 256 + tid, row = c >> 3, d0 = (c & 7) * 8;
        int token = bm * 128 + row, s = token & 2047;
        bf16x8 lo = *(const bf16x8*)&ex[row * 128 + d0];
        bf16x8 hi = *(const bf16x8*)&ex[row * 128 + d0 + 64];
        float4 ca = *(const float4*)(cosT + s * 64 + d0);
        float4 cb = *(const float4*)(cosT + s * 64 + d0 + 4);
        float4 sa = *(const float4*)(sinT + s * 64 + d0);
        float4 sb = *(const float4*)(sinT + s * 64 + d0 + 4);
        float cs[8] = {ca.x, ca.y, ca.z, ca.w, cb.x, cb.y, cb.z, cb.w};
        float sn[8] = {sa.x, sa.y, sa.z, sa.w, sb.x, sb.y, sb.z, sb.w};
        bf16x8 olo, ohi;
#pragma unroll
        for (int jj = 0; jj < 8; jj++) {
          float a = tof(((const bf16*)&lo)[jj]), b2 = tof(((const bf16*)&hi)[jj]);
          ((bf16*)&olo)[jj] = tobf((a * cs[jj] - b2 * sn[jj]) * qs);
          ((bf16*)&ohi)[jj] = tobf((b2 * cs[jj] + a * sn[jj]) * qs);
        }
        bf16* dst = qkv + (size_t)token * 3072 + bn * 128 + d0;
        *(uint4*)dst = *(const uint4*)&olo;
        *(uint4*)(dst + 64) = *(const uint4*)&ohi;
      }
    } else {
      // V: plain coalesced copy-out, 8 uint4 per thread
#pragma unroll
      for (int i = 0; i < 8; i++) {
        int c = i * 256 + tid, row = c >> 4, ch = c & 15;
        int token = bm * 128 + row;
        *(uint4*)(qkv + (size_t)token * 3072 + bn * 128 + ch * 8) =
            *(const uint4*)&ex[row * 128 + ch * 8];
      }
    }
  } else {
    const int r0 = bm * 128 + wm * 64, c0 = bn * 128 + wn * 64;
#pragma unroll
    for (int m = 0; m < 4; m++)
#pragma unroll
      for (int n = 0; n < 4; n++) {
        int col = c0 + n * 16 + llo;
#pragma unroll
        for (int r = 0; r < 4; r++) {
          int row = r0 + m * 16 + lhi * 4 + r;
          if (col >= 3072 && col < 3104) {
            int idx = col - 3072, hh = idx & 15;
            float b = (idx < 16) ? bg1[hh] : bg2[hh];
            float v = 1.f / (1.f + __expf(-(acc[m][n][r] + b)));
            ((idx < 16) ? g1t : g2t)[(size_t)hh * 4096 + row] = v;
          }
        }
      }
  }
}

// ---------------- output GEMM: C = A(4096xK) * Bt(2048xK)^T, fp32 out ----------------
__global__ __launch_bounds__(256, 2) void gemm_out_k(
    const bf16* __restrict__ A, const bf16* __restrict__ Bt, float* __restrict__ C,
    int N, int K) {
  constexpr int BK = 32;
  __shared__ bf16 sA[2][128 * BK];
  __shared__ bf16 sB[2][128 * BK];
  const int tid = threadIdx.x, wave = tid >> 6, lane = tid & 63;
  const int lhi = lane >> 4, llo = lane & 15;
  const int wm = wave >> 1, wn = wave & 1;
  const int bid = blockIdx.x;
  const int swz = (bid & 7) * 64 + (bid >> 3);  // bijective: 512 = 8*64
  const int bm = swz & 31, bn = swz >> 5;       // bn in 0..15
  const bf16* Ag = A + (size_t)bm * 128 * K;
  const bf16* Bg = Bt + (size_t)bn * 128 * K;

  f32x4 acc[4][4];
#pragma unroll
  for (int m = 0; m < 4; m++)
#pragma unroll
    for (int n = 0; n < 4; n++) acc[m][n] = f32x4{0.f, 0.f, 0.f, 0.f};

  auto stage = [&](int buf, int kt) {
#pragma unroll
    for (int i = 0; i < 2; i++) {
      int c = i * 256 + tid, row = c >> 2, c8 = c & 3;
      gload_lds16(Ag + (size_t)row * K + kt * BK + c8 * 8, &sA[buf][c * 8]);
    }
#pragma unroll
    for (int i = 0; i < 2; i++) {
      int c = i * 256 + tid, row = c >> 2, c8 = c & 3;
      gload_lds16(Bg + (size_t)row * K + kt * BK + c8 * 8, &sB[buf][c * 8]);
    }
  };

  const int NT = K / BK;
  stage(0, 0);
  for (int kt = 0; kt < NT; kt++) {
    __syncthreads();
    if (kt + 1 < NT) stage((kt + 1) & 1, kt + 1);
    const bf16* a_ = sA[kt & 1];
    const bf16* b_ = sB[kt & 1];
    bf16x8 af[4], bfr[4];
#pragma unroll
    for (int m = 0; m < 4; m++)
      af[m] = *(const bf16x8*)&a_[(wm * 64 + m * 16 + llo) * BK + lhi * 8];
#pragma unroll
    for (int n = 0; n < 4; n++)
      bfr[n] = *(const bf16x8*)&b_[(wn * 64 + n * 16 + llo) * BK + lhi * 8];
#pragma unroll
    for (int m = 0; m < 4; m++)
#pragma unroll
      for (int n = 0; n < 4; n++)
        acc[m][n] = __builtin_amdgcn_mfma_f32_16x16x32_bf16(af[m], bfr[n], acc[m][n], 0, 0, 0);
  }

  const int r0 = bm * 128 + wm * 64, c0 = bn * 128 + wn * 64;
#pragma unroll
  for (int m = 0; m < 4; m++)
#pragma unroll
    for (int n = 0; n < 4; n++)
#pragma unroll
      for (int r = 0; r < 4; r++)
        C[(size_t)(r0 + m * 16 + lhi * 4 + r) * N + (c0 + n * 16 + llo)] = acc[m][n][r];
}

// ---------------- shared attention epilogue: LN + g1 gate + coalesced store ----------------
DEV void finalize_store(const f32x4 (&o)[8], int wave, int lhi, int llo, int tid,
                        int h, int qt, size_t tok0,
                        const float* __restrict__ g1t, const float* __restrict__ lng,
                        const float* __restrict__ lnb, bf16* stg, bf16* __restrict__ aout) {
  float sum[4] = {0, 0, 0, 0}, sq[4] = {0, 0, 0, 0};
#pragma unroll
  for (int dt = 0; dt < 8; dt++)
#pragma unroll
    for (int r = 0; r < 4; r++) {
      float v = o[dt][r];
      sum[r] += v;
      sq[r] += v * v;
    }
  float mu[4], rstd[4];
#pragma unroll
  for (int r = 0; r < 4; r++) {
    float s1 = sum[r], s2 = sq[r];
    s1 += __shfl_xor(s1, 1); s1 += __shfl_xor(s1, 2); s1 += __shfl_xor(s1, 4); s1 += __shfl_xor(s1, 8);
    s2 += __shfl_xor(s2, 1); s2 += __shfl_xor(s2, 2); s2 += __shfl_xor(s2, 4); s2 += __shfl_xor(s2, 8);
    float m_ = s1 * (1.f / 128.f);
    float var = s2 * (1.f / 128.f) - m_ * m_;
    mu[r] = m_;
    rstd[r] = rsqrtf(var + 1e-5f);
  }
  __syncthreads();  // prior users of stg done
#pragma unroll
  for (int r = 0; r < 4; r++) {
    int lrow = wave * 16 + lhi * 4 + r;
    float gg = g1t[(size_t)h * 4096 + tok0 + qt * 64 + lrow];
#pragma unroll
    for (int dt = 0; dt < 8; dt++) {
      int d = dt * 16 + llo;
      float v = (o[dt][r] - mu[r]) * rstd[r] * lng[d] + lnb[d];
      stg[lrow * 128 + d] = tobf(v * gg);
    }
  }
  __syncthreads();
#pragma unroll
  for (int i = 0; i < 4; i++) {
    int c = i * 256 + tid, lr = c >> 4, c8 = c & 15;
    *(uint4*)(aout + (tok0 + qt * 64 + lr) * 2048 + h * 128 + c8 * 8) =
        *(const uint4*)&stg[lr * 128 + c8 * 8];
  }
}

// cumulative split count before qt (8-tile chunks): pid = pid_base(qt) + s, 80 total
DEV int pid_base(int qt) {
  return qt < 8 ? qt : qt < 16 ? 2 * qt - 8 : qt < 24 ? 3 * qt - 24 : 4 * qt - 48;
}

// LPT-ordered (qt,s) unit table, encoded qt*4+s. Full 8-tile chunks first, then
// remainder chunks by length descending (7..1).
__device__ const unsigned char UNIT_TAB[80] = {
  124,125,126,127,                          // qt31 x4 (len8)
  120,121,122, 116,117,118, 112,113,114,    // qt30..28 (len8)
  108,109,110, 104,105,106, 100,101,102,    // qt27..25
   96, 97, 98,  92, 93, 94,                 // qt24, qt23
   88, 89,  84, 85,  80, 81,  76, 77,       // qt22..19 (len8)
   72, 73,  68, 69,  64, 65,  60, 61,       // qt18..15
   56, 52, 48, 44, 40, 36, 32, 28,          // qt14..7 (len8, single/first)
  123, 90, 57, 24,                          // len7: (30,3)(22,2)(14,1)(6,0)
  119, 86, 53, 20,                          // len6
  115, 82, 49, 16,                          // len5
  111, 78, 45, 12,                          // len4
  107, 74, 41,  8,                          // len3
  103, 70, 37,  4,                          // len2
   99, 66, 33,  0                           // len1
};

// ---------------- split-K causal GQA attention: 2 q-heads, 8-tile LPT units ----------------
// R9 body + T5 setprio (R15) + bf16 partials (R17) + log2 softmax w/ raw v_exp (R19)
// + T13 defer-max THR=8 (log2 units): skip the O/l rescale while pmax <= m_old + 8;
// P bounded by 2^8=256 (bf16 rel-error is magnitude-invariant; final 1/l normalizes).
__global__ __launch_bounds__(256, 2) void attn_split_k(
    const bf16* __restrict__ qkv, const float* __restrict__ g2t,
    const float* __restrict__ g1t, const float* __restrict__ lng,
    const float* __restrict__ lnb,
    bf16* __restrict__ pO, float* __restrict__ pML, bf16* __restrict__ aout) {
  constexpr int S = 2048, LD = 3072;
  const int bid = blockIdx.x;
  const int g = bid & 7, j = bid >> 3;
  const int hp = j & 1, u = j >> 1;
  const int e = UNIT_TAB[u];
  const int qt = e >> 2, s = e & 3;
  const int k0 = s * 8, k1 = min(s * 8 + 8, qt + 1);
  const bool partial = (qt >= 8);

  const int b = g >> 2, kvh = g & 3, h0 = kvh * 4 + hp * 2;
  const int tid = threadIdx.x, wave = tid >> 6, lane = tid & 63;
  const int lhi = lane >> 4, llo = lane & 15;
  const size_t tok0 = (size_t)b * S;

  __shared__ bf16 sK[64 * 128];      // [kv][d], XOR-swizzled ((row&7)<<3 on element idx)
  __shared__ bf16 sV[128 * 64];      // [d][kv] transposed, XOR-swizzled ((d&7)<<3)
  __shared__ bf16 sP[4][2][16][72];  // per-wave, per-head P tile, padded

  const int qrow0 = qt * 64 + wave * 16;

  bf16x8 qf[2][4];
#pragma unroll
  for (int hh = 0; hh < 2; hh++) {
    const bf16* qg = qkv + (tok0 + qrow0 + llo) * LD + (h0 + hh) * 128;
#pragma unroll
    for (int dc = 0; dc < 4; dc++) qf[hh][dc] = *(const bf16x8*)(qg + dc * 32 + lhi * 8);
  }

  f32x4 oacc[2][8];
#pragma unroll
  for (int hh = 0; hh < 2; hh++)
#pragma unroll
    for (int i = 0; i < 8; i++) oacc[hh][i] = f32x4{0.f, 0.f, 0.f, 0.f};
  float mrow[2][4], lrow[2][4];
#pragma unroll
  for (int hh = 0; hh < 2; hh++)
#pragma unroll
    for (int r = 0; r < 4; r++) { mrow[hh][r] = -1e30f; lrow[hh][r] = 0.f; }

  uint4 kreg[4];
  bf16x8 vreg[4];
  float gvreg[2];
  const int vdg = tid >> 4;   // d-group: 8 d elems
  const int vkg = tid & 15;   // kv-group: 4 kv rows

  auto issue_loads = [&](int kt) {
#pragma unroll
    for (int i = 0; i < 4; i++) {
      int c = i * 256 + tid, row = c >> 4, c8 = c & 15;
      kreg[i] = *(const uint4*)(qkv + (tok0 + kt * 64 + row) * LD + 2048 + kvh * 128 + c8 * 8);
    }
#pragma unroll
    for (int r = 0; r < 4; r++)
      vreg[r] = *(const bf16x8*)(qkv + (tok0 + kt * 64 + vkg * 4 + r) * LD + 2560 +
                                 kvh * 128 + vdg * 8);
#pragma unroll
    for (int hh = 0; hh < 2; hh++)
      gvreg[hh] = g2t[(size_t)(h0 + hh) * 4096 + tok0 + kt * 64 + lane];
  };

  auto write_lds = [&]() {
#pragma unroll
    for (int i = 0; i < 4; i++) {
      int c = i * 256 + tid, row = c >> 4, c8 = c & 15;
      int eidx = (row * 128 + c8 * 8) ^ ((row & 7) << 3);
      *(uint4*)&sK[eidx] = kreg[i];
    }
#pragma unroll
    for (int e2 = 0; e2 < 8; e2++) {
      int d = vdg * 8 + e2;          // d & 7 == e2
      uint32_t lo = (uint32_t)(unsigned short)vreg[0][e2] |
                    ((uint32_t)(unsigned short)vreg[1][e2] << 16);
      uint32_t hi = (uint32_t)(unsigned short)vreg[2][e2] |
                    ((uint32_t)(unsigned short)vreg[3][e2] << 16);
      int eidx = (d * 64 + vkg * 4) ^ (e2 << 3);
      uint2 pk; pk.x = lo; pk.y = hi;
      *(uint2*)&sV[eidx] = pk;
    }
  };

  issue_loads(k0);
  for (int kt = k0; kt < k1; kt++) {
    __syncthreads();  // previous tile's LDS reads complete before overwrite
    write_lds();      // vmcnt wait lands here (data long arrived)
    float gv0 = gvreg[0], gv1 = gvreg[1];
    if (kt + 1 < k1) issue_loads(kt + 1);  // registers only; in flight across barrier+compute
    __syncthreads();  // LDS writes visible

    const bool diag = (kt == qt);
#pragma unroll
    for (int hh = 0; hh < 2; hh++) {
      // ---- QK^T (T5: raise wave priority through the MFMA cluster) ----
      f32x4 sc[4];
      __builtin_amdgcn_s_setprio(1);
#pragma unroll
      for (int ct = 0; ct < 4; ct++) {
        f32x4 acc = f32x4{0.f, 0.f, 0.f, 0.f};
#pragma unroll
        for (int dc = 0; dc < 4; dc++) {
          int row = ct * 16 + llo;
          bf16x8 kf = *(const bf16x8*)&sK[(row * 128 + dc * 32 + lhi * 8) ^ ((row & 7) << 3)];
          acc = __builtin_amdgcn_mfma_f32_16x16x32_bf16(qf[hh][dc], kf, acc, 0, 0, 0);
        }
        sc[ct] = acc;
      }
      __builtin_amdgcn_s_setprio(0);
      // ---- causal mask + online softmax, log2 domain, defer-max THR=8 ----
      float pm[4] = {-1e30f, -1e30f, -1e30f, -1e30f};
#pragma unroll
      for (int ct = 0; ct < 4; ct++) {
        int kv = kt * 64 + ct * 16 + llo;
#pragma unroll
        for (int r = 0; r < 4; r++) {
          float s_ = sc[ct][r];
          if (diag && kv > qrow0 + lhi * 4 + r) s_ = -1e30f;
          sc[ct][r] = s_;
          pm[r] = fmaxf(pm[r], s_);
        }
      }
#pragma unroll
      for (int r = 0; r < 4; r++) {
        float v = pm[r];
        v = fmaxf(v, __shfl_xor(v, 1));
        v = fmaxf(v, __shfl_xor(v, 2));
        v = fmaxf(v, __shfl_xor(v, 4));
        v = fmaxf(v, __shfl_xor(v, 8));
        pm[r] = v;
      }
      int need = 0;
#pragma unroll
      for (int r = 0; r < 4; r++) need |= (pm[r] > mrow[hh][r] + 8.f) ? 1 : 0;
      if (__any(need)) {
#pragma unroll
        for (int r = 0; r < 4; r++) {
          float mnew = fmaxf(mrow[hh][r], pm[r]);
          float al = fexp2(mrow[hh][r] - mnew);
          mrow[hh][r] = mnew;
          lrow[hh][r] *= al;
#pragma unroll
          for (int i = 0; i < 8; i++) oacc[hh][i][r] *= al;
        }
      }
      float gv = hh ? gv1 : gv0;
      float g2v[4];
#pragma unroll
      for (int ct = 0; ct < 4; ct++) g2v[ct] = __shfl(gv, ct * 16 + llo);
      float rs[4] = {0.f, 0.f, 0.f, 0.f};
#pragma unroll
      for (int ct = 0; ct < 4; ct++) {
#pragma unroll
        for (int r = 0; r < 4; r++) {
          float p = fexp2(sc[ct][r] - mrow[hh][r]);
          rs[r] += p;  // softmax denom uses UNGATED p
          sP[wave][hh][lhi * 4 + r][ct * 16 + llo] = tobf(p * g2v[ct]);
        }
      }
#pragma unroll
      for (int r = 0; r < 4; r++) {
        float v = rs[r];
        v += __shfl_xor(v, 1); v += __shfl_xor(v, 2); v += __shfl_xor(v, 4); v += __shfl_xor(v, 8);
        lrow[hh][r] += v;
      }
    }
    // ---- PV: both heads share each V fragment (T5 around MFMA cluster) ----
    __builtin_amdgcn_s_setprio(1);
#pragma unroll
    for (int kc = 0; kc < 2; kc++) {
      bf16x8 pf0 = *(const bf16x8*)&sP[wave][0][llo][kc * 32 + lhi * 8];
      bf16x8 pf1 = *(const bf16x8*)&sP[wave][1][llo][kc * 32 + lhi * 8];
#pragma unroll
      for (int dt = 0; dt < 8; dt++) {
        int d = dt * 16 + llo;
        bf16x8 vf = *(const bf16x8*)&sV[(d * 64 + kc * 32 + lhi * 8) ^ ((d & 7) << 3)];
        oacc[0][dt] = __builtin_amdgcn_mfma_f32_16x16x32_bf16(pf0, vf, oacc[0][dt], 0, 0, 0);
        oacc[1][dt] = __builtin_amdgcn_mfma_f32_16x16x32_bf16(pf1, vf, oacc[1][dt], 0, 0, 0);
      }
    }
    __builtin_amdgcn_s_setprio(0);
  }

  if (partial) {
    const int pid = pid_base(qt) + s;
#pragma unroll
    for (int hh = 0; hh < 2; hh++) {
      const int sub = (g * 2 + hp) * 2 + hh;
      uint2* dst = (uint2*)pO + (size_t)(pid * 32 + sub) * 2048;
#pragma unroll
      for (int dt = 0; dt < 8; dt++) {
        bf16 pk[4];
#pragma unroll
        for (int r = 0; r < 4; r++) pk[r] = tobf(oacc[hh][dt][r]);
        uint2 uu; __builtin_memcpy(&uu, pk, 8);
        dst[(wave * 8 + dt) * 64 + lane] = uu;
      }
      if (llo == 0) {
#pragma unroll
        for (int r = 0; r < 4; r++) {
          int row = wave * 16 + lhi * 4 + r;
          float* pm = pML + ((size_t)(pid * 32 + sub) * 64 + row) * 2;
          pm[0] = mrow[hh][r];
          pm[1] = lrow[hh][r];
        }
      }
    }
  } else {
#pragma unroll
    for (int hh = 0; hh < 2; hh++) {
      float inv[4];
#pragma unroll
      for (int r = 0; r < 4; r++) inv[r] = 1.f / lrow[hh][r];
      f32x4 o[8];
#pragma unroll
      for (int dt = 0; dt < 8; dt++)
#pragma unroll
        for (int r = 0; r < 4; r++) o[dt][r] = oacc[hh][dt][r] * inv[r];
      finalize_store(o, wave, lhi, llo, tid, h0 + hh, qt, tok0, g1t, lng, lnb, sK, aout);
    }
  }
}

// ---------------- combine ns partials (2..4) + LN + g1 gate ----------------
// 384 blocks; m values are in log2 domain (weights via raw v_exp_f32, matching split).
__global__ __launch_bounds__(256) void attn_combine_k(
    const bf16* __restrict__ pO, const float* __restrict__ pML,
    const float* __restrict__ g1t, const float* __restrict__ lng,
    const float* __restrict__ lnb, bf16* __restrict__ aout) {
  __shared__ bf16 stg[64 * 128];
  const int bid = blockIdx.x;
  const int g = bid & 7, j = bid >> 3;
  const int hp = j & 1, qtc = j >> 1;
  const int qt = 8 + qtc;
  const int ns = (qt < 16) ? 2 : (qt < 24) ? 3 : 4;
  const int p0id = pid_base(qt);
  const int b = g >> 2, kvh = g & 3, h0 = kvh * 4 + hp * 2;
  const int tid = threadIdx.x, wave = tid >> 6, lane = tid & 63;
  const int lhi = lane >> 4, llo = lane & 15;
  const size_t tok0 = (size_t)b * 2048;
#pragma unroll
  for (int hh = 0; hh < 2; hh++) {
    const int sub = (g * 2 + hp) * 2 + hh;
    float w[4][4], inv[4];
#pragma unroll
    for (int r = 0; r < 4; r++) {
      int row = wave * 16 + lhi * 4 + r;
      float m[4], l[4], ms = -1e30f;
#pragma unroll
      for (int sp = 0; sp < 4; sp++)
        if (sp < ns) {
          const float* q = pML + ((size_t)((p0id + sp) * 32 + sub) * 64 + row) * 2;
          m[sp] = q[0]; l[sp] = q[1];
          ms = fmaxf(ms, m[sp]);
        }
      float L = 0.f;
#pragma unroll
      for (int sp = 0; sp < 4; sp++)
        if (sp < ns) { w[sp][r] = fexp2(m[sp] - ms); L += w[sp][r] * l[sp]; }
      inv[r] = 1.f / L;
    }
    f32x4 o[8];
#pragma unroll
    for (int dt = 0; dt < 8; dt++) {
      f32x4 a = f32x4{0.f, 0.f, 0.f, 0.f};
#pragma unroll
      for (int sp = 0; sp < 4; sp++)
        if (sp < ns) {
          uint2 uu = ((const uint2*)pO + (size_t)((p0id + sp) * 32 + sub) * 2048)
                         [(wave * 8 + dt) * 64 + lane];
          bf16 pk[4]; __builtin_memcpy(pk, &uu, 8);
#pragma unroll
          for (int r = 0; r < 4; r++) a[r] += w[sp][r] * tof(pk[r]);
        }
#pragma unroll
      for (int r = 0; r < 4; r++) o[dt][r] = a[r] * inv[r];
    }
    finalize_store(o, wave, lhi, llo, tid, h0 + hh, qt, tok0, g1t, lng, lnb, stg, aout);
  }
}

// ---------------- launch ----------------
extern "C" void kernel_launch(void* const* d_in, const int* in_sizes, int n_in,
                              void* d_out, int out_size, void* d_ws, size_t ws_size,
                              hipStream_t stream) {
  (void)in_sizes; (void)n_in; (void)out_size; (void)ws_size;
  const float* X   = (const float*)d_in[0];
  const int*   pos = (const int*)d_in[1];
  const float* Wq  = (const float*)d_in[2];
  const float* Wk  = (const float*)d_in[3];
  const float* Wv  = (const float*)d_in[4];
  const float* Wo  = (const float*)d_in[5];
  const float* Wg1 = (const float*)d_in[6];
  const float* bg1 = (const float*)d_in[7];
  const float* Wg2 = (const float*)d_in[8];
  const float* bg2 = (const float*)d_in[9];
  const float* lng = (const float*)d_in[10];
  const float* lnb = (const float*)d_in[11];

  char* ws = (char*)d_ws;
  size_t off = 0;
  auto alloc = [&](size_t bytes) {
    void* p = ws + off;
    off += (bytes + 255) & ~(size_t)255;
    return p;
  };
  bf16*  WT   = (bf16*)alloc(3200ull * 2048 * 2);   // [Wq^T; Wk^T; Wv^T; Wg1^T; Wg2^T; pad]
  bf16*  WoT  = (bf16*)alloc(2048ull * 2048 * 2);
  bf16*  Xbf  = (bf16*)alloc(4096ull * 2048 * 2);
  bf16*  qkv  = (bf16*)alloc(4096ull * 3072 * 2);
  bf16*  attn = (bf16*)alloc(4096ull * 2048 * 2);
  float* cosT = (float*)alloc(2048ull * 64 * 4);
  float* sinT = (float*)alloc(2048ull * 64 * 4);
  float* g1t  = (float*)alloc(16ull * 4096 * 4);    // [head][token]
  float* g2t  = (float*)alloc(16ull * 4096 * 4);
  bf16*  pO   = (bf16*)alloc(80ull * 32 * 2048 * 8);  // [pid][sub] bf16x4-coalesced partials
  float* pML  = (float*)alloc(80ull * 32 * 64 * 2 * 4);

  // all prep in one launch: weight transposes (128B-segment writes), X cast,
  // rope tables, gate-weight transpose
  prep_all_k<<<5152, 256, 0, stream>>>(X, pos, Wq, Wk, Wv, Wo, Wg1, Wg2,
                                       WT, WoT, Xbf, cosT, sinT);

  // [qkv | g1t | g2t] = Xbf @ WT^T  (4096 x 3200), RoPE + Q log2-prescale fused
  gemm_qkv_k<<<800, 256, 0, stream>>>(Xbf, WT, qkv, g1t, g2t, bg1, bg2, cosT, sinT);
  attn_split_k<<<1280, 256, 0, stream>>>(qkv, g2t, g1t, lng, lnb, pO, pML, attn);
  attn_combine_k<<<384, 256, 0, stream>>>(pO, pML, g1t, lng, lnb, attn);
  // out = attn @ Wo  (4096 x 2048), fp32
  gemm_out_k<<<512, 256, 0, stream>>>(attn, WoT, (float*)d_out, 2048, 2048);
}

// Round 21
// 276.004 us; speedup vs baseline: 1.0451x; 1.0031x over previous
//
#include <hip/hip_runtime.h>
#include <hip/hip_bf16.h>
#include <stdint.h>
#include <string.h>

using bf16 = __hip_bfloat16;
typedef __attribute__((ext_vector_type(8))) short bf16x8;   // 8 bf16 (4 VGPRs) MFMA A/B frag
typedef __attribute__((ext_vector_type(4))) float f32x4;    // MFMA C/D frag

#define DEV static __device__ __forceinline__

DEV bf16 tobf(float f) { return __float2bfloat16(f); }
DEV float tof(bf16 h) { return __bfloat162float(h); }
DEV float fexp2(float x) { return __builtin_amdgcn_exp2f(x); }  // bare v_exp_f32 (args <= 0 here)

// async global->LDS, 16B per lane. LDS dest semantics: wave-uniform base + lane*16.
DEV void gload_lds16(const void* g, void* l) {
  __builtin_amdgcn_global_load_lds((__attribute__((address_space(1))) void*)g,
                                   (__attribute__((address_space(3))) void*)l,
                                   16, 0, 0);
}

// ---------------- fused prep kernel ----------------
// One flat grid, 5152 blocks x 256 threads:
//   t <  2560 : 64x64 transpose+cast tiles over {Wq,Wk,Wv,Wo} -> WT / WoT
//   t <  4608 : cast X fp32 -> bf16 (4 float4/thread)
//   t <  5120 : rope cos/sin tables (4 s-rows/block)
//   else      : Wg1/Wg2 transpose into WT rows 3072..3103
__global__ __launch_bounds__(256) void prep_all_k(
    const float* __restrict__ X, const int* __restrict__ pos,
    const float* __restrict__ Wq, const float* __restrict__ Wk,
    const float* __restrict__ Wv, const float* __restrict__ Wo,
    const float* __restrict__ Wg1, const float* __restrict__ Wg2,
    bf16* __restrict__ WT, bf16* __restrict__ WoT, bf16* __restrict__ Xbf,
    float* __restrict__ cosT, float* __restrict__ sinT) {
  __shared__ float tile[64][65];
  const int t = blockIdx.x, tid = threadIdx.x;
  if (t < 2560) {
    const float* src; bf16* dst; int N, kb, nb;
    if (t < 1024)      { src = Wq; dst = WT;                  N = 2048; kb = (t >> 5) << 6;          nb = (t & 31) << 6; }
    else if (t < 1280) { int l = t - 1024; src = Wk; dst = WT + 2048ull * 2048; N = 512; kb = (l >> 3) << 6; nb = (l & 7) << 6; }
    else if (t < 1536) { int l = t - 1280; src = Wv; dst = WT + 2560ull * 2048; N = 512; kb = (l >> 3) << 6; nb = (l & 7) << 6; }
    else               { int l = t - 1536; src = Wo; dst = WoT;                N = 2048; kb = (l >> 5) << 6; nb = (l & 31) << 6; }
    const int c = tid & 63, r0 = tid >> 6;
#pragma unroll
    for (int i = 0; i < 16; i++) {
      int r = i * 4 + r0;
      tile[r][c] = src[(size_t)(kb + r) * N + nb + c];
    }
    __syncthreads();
    const int q = tid & 7;
#pragma unroll
    for (int p = 0; p < 2; p++) {
      int n = p * 32 + (tid >> 3);
      bf16 pk[8];
#pragma unroll
      for (int j = 0; j < 8; j++) pk[j] = tobf(tile[q * 8 + j][n]);
      uint4 u; __builtin_memcpy(&u, pk, 16);
      *(uint4*)(dst + (size_t)(nb + n) * 2048 + kb + q * 8) = u;
    }
  } else if (t < 4608) {
    const int blk = t - 2560;
#pragma unroll
    for (int j = 0; j < 4; j++) {
      int idx = blk * 1024 + j * 256 + tid;
      float4 v = ((const float4*)X)[idx];
      bf16 p4[4] = {tobf(v.x), tobf(v.y), tobf(v.z), tobf(v.w)};
      uint2 p; __builtin_memcpy(&p, p4, 8);
      ((uint2*)Xbf)[idx] = p;
    }
  } else if (t < 5120) {
    const int blk = t - 4608;
    int s = blk * 4 + (tid >> 6), i = tid & 63;
    double inv = exp(-((double)(2 * i) / 128.0) * log(10000.0));
    float f = (float)pos[s] * (float)inv;
    cosT[s * 64 + i] = cosf(f);
    sinT[s * 64 + i] = sinf(f);
  } else {
    const int blk = t - 5120;
    int g = blk >> 4, r = blk & 15;
    const float* src = g ? Wg2 : Wg1;
    bf16* dst = WT + (size_t)(3072 + g * 16 + r) * 2048;
    for (int k = tid; k < 2048; k += 256) dst[k] = tobf(src[(size_t)k * 16 + r]);
  }
}

// ---------------- QKV+gates GEMM with fused RoPE: [qkv | g1t | g2t] = Xbf @ WT^T ----
// Q heads (bn<16) are additionally pre-scaled by 1/sqrt(128)*log2(e) so attention's
// QK^T lands directly in the log2 softmax domain (saves scale-mul + exp pre-mul there).
// launch_bounds (256,3): 3 blocks/CU (VGPR cap 170 fits the m97-class K-loop ~164;
// grid 800 at 768 resident -> 1.04 fill rounds vs 1.56 at 2/CU).
__global__ __launch_bounds__(256, 3) void gemm_qkv_k(
    const bf16* __restrict__ A, const bf16* __restrict__ Bt, bf16* __restrict__ qkv,
    float* __restrict__ g1t, float* __restrict__ g2t,
    const float* __restrict__ bg1, const float* __restrict__ bg2,
    const float* __restrict__ cosT, const float* __restrict__ sinT) {
  constexpr int BK = 32, K = 2048;
  __shared__ bf16 smem[16384];  // sA = smem[0..8191] (2 bufs), sB = smem[8192..16383]; ex = all
  const int tid = threadIdx.x, wave = tid >> 6, lane = tid & 63;
  const int lhi = lane >> 4, llo = lane & 15;
  const int wm = wave >> 1, wn = wave & 1;
  const int bid = blockIdx.x;
  const int swz = (bid & 7) * 100 + (bid >> 3);  // bijective: 800 = 8*100
  const int bm = swz & 31, bn = swz >> 5;        // bn in 0..24
  const bf16* Ag = A + (size_t)bm * 128 * K;
  const bf16* Bg = Bt + (size_t)bn * 128 * K;

  f32x4 acc[4][4];
#pragma unroll
  for (int m = 0; m < 4; m++)
#pragma unroll
    for (int n = 0; n < 4; n++) acc[m][n] = f32x4{0.f, 0.f, 0.f, 0.f};

  auto stage = [&](int buf, int kt) {
#pragma unroll
    for (int i = 0; i < 2; i++) {
      int c = i * 256 + tid, row = c >> 2, c8 = c & 3;
      gload_lds16(Ag + (size_t)row * K + kt * BK + c8 * 8, smem + buf * 4096 + c * 8);
    }
#pragma unroll
    for (int i = 0; i < 2; i++) {
      int c = i * 256 + tid, row = c >> 2, c8 = c & 3;
      gload_lds16(Bg + (size_t)row * K + kt * BK + c8 * 8, smem + 8192 + buf * 4096 + c * 8);
    }
  };

  const int NT = K / BK;
  stage(0, 0);
  for (int kt = 0; kt < NT; kt++) {
    __syncthreads();
    if (kt + 1 < NT) stage((kt + 1) & 1, kt + 1);
    const bf16* a_ = smem + (kt & 1) * 4096;
    const bf16* b_ = smem + 8192 + (kt & 1) * 4096;
    bf16x8 af[4], bfr[4];
#pragma unroll
    for (int m = 0; m < 4; m++)
      af[m] = *(const bf16x8*)&a_[(wm * 64 + m * 16 + llo) * BK + lhi * 8];
#pragma unroll
    for (int n = 0; n < 4; n++)
      bfr[n] = *(const bf16x8*)&b_[(wn * 64 + n * 16 + llo) * BK + lhi * 8];
#pragma unroll
    for (int m = 0; m < 4; m++)
#pragma unroll
      for (int n = 0; n < 4; n++)
        acc[m][n] = __builtin_amdgcn_mfma_f32_16x16x32_bf16(af[m], bfr[n], acc[m][n], 0, 0, 0);
  }

  if (bn < 24) {
    // stage full 128x128 tile as bf16 into LDS (over sA/sB)
    bf16* ex = smem;
    __syncthreads();  // all waves done reading sA/sB
#pragma unroll
    for (int m = 0; m < 4; m++)
#pragma unroll
      for (int n = 0; n < 4; n++) {
        int wrow = wm * 64 + m * 16 + lhi * 4;
        int wc = wn * 64 + n * 16 + llo;
#pragma unroll
        for (int r = 0; r < 4; r++) ex[(wrow + r) * 128 + wc] = tobf(acc[m][n][r]);
      }
    __syncthreads();
    if (bn < 20) {
      // RoPE: 128 rows x 8 lo-chunks (8 cols), 4 per thread.
      // Q heads: extra pre-scale by 1/sqrt(128)*log2(e) for log2-domain softmax.
      const float qs = (bn < 16) ? 0.12751651545f : 1.0f;
#pragma unroll
      for (int i = 0; i < 4; i++) {
        int c = i * 256 + tid, row = c >> 3, d0 = (c & 7) * 8;
        int token = bm * 128 + row, s = token & 2047;
        bf16x8 lo = *(const bf16x8*)&ex[row * 128 + d0];
        bf16x8 hi = *(const bf16x8*)&ex[row * 128 + d0 + 64];
        float4 ca = *(const float4*)(cosT + s * 64 + d0);
        float4 cb = *(const float4*)(cosT + s * 64 + d0 + 4);
        float4 sa = *(const float4*)(sinT + s * 64 + d0);
        float4 sb = *(const float4*)(sinT + s * 64 + d0 + 4);
        float cs[8] = {ca.x, ca.y, ca.z, ca.w, cb.x, cb.y, cb.z, cb.w};
        float sn[8] = {sa.x, sa.y, sa.z, sa.w, sb.x, sb.y, sb.z, sb.w};
        bf16x8 olo, ohi;
#pragma unroll
        for (int jj = 0; jj < 8; jj++) {
          float a = tof(((const bf16*)&lo)[jj]), b2 = tof(((const bf16*)&hi)[jj]);
          ((bf16*)&olo)[jj] = tobf((a * cs[jj] - b2 * sn[jj]) * qs);
          ((bf16*)&ohi)[jj] = tobf((b2 * cs[jj] + a * sn[jj]) * qs);
        }
        bf16* dst = qkv + (size_t)token * 3072 + bn * 128 + d0;
        *(uint4*)dst = *(const uint4*)&olo;
        *(uint4*)(dst + 64) = *(const uint4*)&ohi;
      }
    } else {
      // V: plain coalesced copy-out, 8 uint4 per thread
#pragma unroll
      for (int i = 0; i < 8; i++) {
        int c = i * 256 + tid, row = c >> 4, ch = c & 15;
        int token = bm * 128 + row;
        *(uint4*)(qkv + (size_t)token * 3072 + bn * 128 + ch * 8) =
            *(const uint4*)&ex[row * 128 + ch * 8];
      }
    }
  } else {
    const int r0 = bm * 128 + wm * 64, c0 = bn * 128 + wn * 64;
#pragma unroll
    for (int m = 0; m < 4; m++)
#pragma unroll
      for (int n = 0; n < 4; n++) {
        int col = c0 + n * 16 + llo;
#pragma unroll
        for (int r = 0; r < 4; r++) {
          int row = r0 + m * 16 + lhi * 4 + r;
          if (col >= 3072 && col < 3104) {
            int idx = col - 3072, hh = idx & 15;
            float b = (idx < 16) ? bg1[hh] : bg2[hh];
            float v = 1.f / (1.f + __expf(-(acc[m][n][r] + b)));
            ((idx < 16) ? g1t : g2t)[(size_t)hh * 4096 + row] = v;
          }
        }
      }
  }
}

// ---------------- output GEMM: C = A(4096xK) * Bt(2048xK)^T, fp32 out ----------------
// launch_bounds (256,3): all 512 blocks resident in one round + extra TLP for the
// barrier-drain stall.
__global__ __launch_bounds__(256, 3) void gemm_out_k(
    const bf16* __restrict__ A, const bf16* __restrict__ Bt, float* __restrict__ C,
    int N, int K) {
  constexpr int BK = 32;
  __shared__ bf16 sA[2][128 * BK];
  __shared__ bf16 sB[2][128 * BK];
  const int tid = threadIdx.x, wave = tid >> 6, lane = tid & 63;
  const int lhi = lane >> 4, llo = lane & 15;
  const int wm = wave >> 1, wn = wave & 1;
  const int bid = blockIdx.x;
  const int swz = (bid & 7) * 64 + (bid >> 3);  // bijective: 512 = 8*64
  const int bm = swz & 31, bn = swz >> 5;       // bn in 0..15
  const bf16* Ag = A + (size_t)bm * 128 * K;
  const bf16* Bg = Bt + (size_t)bn * 128 * K;

  f32x4 acc[4][4];
#pragma unroll
  for (int m = 0; m < 4; m++)
#pragma unroll
    for (int n = 0; n < 4; n++) acc[m][n] = f32x4{0.f, 0.f, 0.f, 0.f};

  auto stage = [&](int buf, int kt) {
#pragma unroll
    for (int i = 0; i < 2; i++) {
      int c = i * 256 + tid, row = c >> 2, c8 = c & 3;
      gload_lds16(Ag + (size_t)row * K + kt * BK + c8 * 8, &sA[buf][c * 8]);
    }
#pragma unroll
    for (int i = 0; i < 2; i++) {
      int c = i * 256 + tid, row = c >> 2, c8 = c & 3;
      gload_lds16(Bg + (size_t)row * K + kt * BK + c8 * 8, &sB[buf][c * 8]);
    }
  };

  const int NT = K / BK;
  stage(0, 0);
  for (int kt = 0; kt < NT; kt++) {
    __syncthreads();
    if (kt + 1 < NT) stage((kt + 1) & 1, kt + 1);
    const bf16* a_ = sA[kt & 1];
    const bf16* b_ = sB[kt & 1];
    bf16x8 af[4], bfr[4];
#pragma unroll
    for (int m = 0; m < 4; m++)
      af[m] = *(const bf16x8*)&a_[(wm * 64 + m * 16 + llo) * BK + lhi * 8];
#pragma unroll
    for (int n = 0; n < 4; n++)
      bfr[n] = *(const bf16x8*)&b_[(wn * 64 + n * 16 + llo) * BK + lhi * 8];
#pragma unroll
    for (int m = 0; m < 4; m++)
#pragma unroll
      for (int n = 0; n < 4; n++)
        acc[m][n] = __builtin_amdgcn_mfma_f32_16x16x32_bf16(af[m], bfr[n], acc[m][n], 0, 0, 0);
  }

  const int r0 = bm * 128 + wm * 64, c0 = bn * 128 + wn * 64;
#pragma unroll
  for (int m = 0; m < 4; m++)
#pragma unroll
    for (int n = 0; n < 4; n++)
#pragma unroll
      for (int r = 0; r < 4; r++)
        C[(size_t)(r0 + m * 16 + lhi * 4 + r) * N + (c0 + n * 16 + llo)] = acc[m][n][r];
}

// ---------------- shared attention epilogue: LN + g1 gate + coalesced store ----------------
DEV void finalize_store(const f32x4 (&o)[8], int wave, int lhi, int llo, int tid,
                        int h, int qt, size_t tok0,
                        const float* __restrict__ g1t, const float* __restrict__ lng,
                        const float* __restrict__ lnb, bf16* stg, bf16* __restrict__ aout) {
  float sum[4] = {0, 0, 0, 0}, sq[4] = {0, 0, 0, 0};
#pragma unroll
  for (int dt = 0; dt < 8; dt++)
#pragma unroll
    for (int r = 0; r < 4; r++) {
      float v = o[dt][r];
      sum[r] += v;
      sq[r] += v * v;
    }
  float mu[4], rstd[4];
#pragma unroll
  for (int r = 0; r < 4; r++) {
    float s1 = sum[r], s2 = sq[r];
    s1 += __shfl_xor(s1, 1); s1 += __shfl_xor(s1, 2); s1 += __shfl_xor(s1, 4); s1 += __shfl_xor(s1, 8);
    s2 += __shfl_xor(s2, 1); s2 += __shfl_xor(s2, 2); s2 += __shfl_xor(s2, 4); s2 += __shfl_xor(s2, 8);
    float m_ = s1 * (1.f / 128.f);
    float var = s2 * (1.f / 128.f) - m_ * m_;
    mu[r] = m_;
    rstd[r] = rsqrtf(var + 1e-5f);
  }
  __syncthreads();  // prior users of stg done
#pragma unroll
  for (int r = 0; r < 4; r++) {
    int lrow = wave * 16 + lhi * 4 + r;
    float gg = g1t[(size_t)h * 4096 + tok0 + qt * 64 + lrow];
#pragma unroll
    for (int dt = 0; dt < 8; dt++) {
      int d = dt * 16 + llo;
      float v = (o[dt][r] - mu[r]) * rstd[r] * lng[d] + lnb[d];
      stg[lrow * 128 + d] = tobf(v * gg);
    }
  }
  __syncthreads();
#pragma unroll
  for (int i = 0; i < 4; i++) {
    int c = i * 256 + tid, lr = c >> 4, c8 = c & 15;
    *(uint4*)(aout + (tok0 + qt * 64 + lr) * 2048 + h * 128 + c8 * 8) =
        *(const uint4*)&stg[lr * 128 + c8 * 8];
  }
}

// cumulative split count before qt (8-tile chunks): pid = pid_base(qt) + s, 80 total
DEV int pid_base(int qt) {
  return qt < 8 ? qt : qt < 16 ? 2 * qt - 8 : qt < 24 ? 3 * qt - 24 : 4 * qt - 48;
}

// LPT-ordered (qt,s) unit table, encoded qt*4+s. Full 8-tile chunks first, then
// remainder chunks by length descending (7..1).
__device__ const unsigned char UNIT_TAB[80] = {
  124,125,126,127,                          // qt31 x4 (len8)
  120,121,122, 116,117,118, 112,113,114,    // qt30..28 (len8)
  108,109,110, 104,105,106, 100,101,102,    // qt27..25
   96, 97, 98,  92, 93, 94,                 // qt24, qt23
   88, 89,  84, 85,  80, 81,  76, 77,       // qt22..19 (len8)
   72, 73,  68, 69,  64, 65,  60, 61,       // qt18..15
   56, 52, 48, 44, 40, 36, 32, 28,          // qt14..7 (len8, single/first)
  123, 90, 57, 24,                          // len7: (30,3)(22,2)(14,1)(6,0)
  119, 86, 53, 20,                          // len6
  115, 82, 49, 16,                          // len5
  111, 78, 45, 12,                          // len4
  107, 74, 41,  8,                          // len3
  103, 70, 37,  4,                          // len2
   99, 66, 33,  0                           // len1
};

// ---------------- split-K causal GQA attention: 2 q-heads, 8-tile LPT units ----------------
// R9 body + T5 setprio (R15) + bf16 partials (R17) + log2 softmax w/ raw v_exp (R19)
// + T13 defer-max THR=8 (R20). Converged configuration.
__global__ __launch_bounds__(256, 2) void attn_split_k(
    const bf16* __restrict__ qkv, const float* __restrict__ g2t,
    const float* __restrict__ g1t, const float* __restrict__ lng,
    const float* __restrict__ lnb,
    bf16* __restrict__ pO, float* __restrict__ pML, bf16* __restrict__ aout) {
  constexpr int S = 2048, LD = 3072;
  const int bid = blockIdx.x;
  const int g = bid & 7, j = bid >> 3;
  const int hp = j & 1, u = j >> 1;
  const int e = UNIT_TAB[u];
  const int qt = e >> 2, s = e & 3;
  const int k0 = s * 8, k1 = min(s * 8 + 8, qt + 1);
  const bool partial = (qt >= 8);

  const int b = g >> 2, kvh = g & 3, h0 = kvh * 4 + hp * 2;
  const int tid = threadIdx.x, wave = tid >> 6, lane = tid & 63;
  const int lhi = lane >> 4, llo = lane & 15;
  const size_t tok0 = (size_t)b * S;

  __shared__ bf16 sK[64 * 128];      // [kv][d], XOR-swizzled ((row&7)<<3 on element idx)
  __shared__ bf16 sV[128 * 64];      // [d][kv] transposed, XOR-swizzled ((d&7)<<3)
  __shared__ bf16 sP[4][2][16][72];  // per-wave, per-head P tile, padded

  const int qrow0 = qt * 64 + wave * 16;

  bf16x8 qf[2][4];
#pragma unroll
  for (int hh = 0; hh < 2; hh++) {
    const bf16* qg = qkv + (tok0 + qrow0 + llo) * LD + (h0 + hh) * 128;
#pragma unroll
    for (int dc = 0; dc < 4; dc++) qf[hh][dc] = *(const bf16x8*)(qg + dc * 32 + lhi * 8);
  }

  f32x4 oacc[2][8];
#pragma unroll
  for (int hh = 0; hh < 2; hh++)
#pragma unroll
    for (int i = 0; i < 8; i++) oacc[hh][i] = f32x4{0.f, 0.f, 0.f, 0.f};
  float mrow[2][4], lrow[2][4];
#pragma unroll
  for (int hh = 0; hh < 2; hh++)
#pragma unroll
    for (int r = 0; r < 4; r++) { mrow[hh][r] = -1e30f; lrow[hh][r] = 0.f; }

  uint4 kreg[4];
  bf16x8 vreg[4];
  float gvreg[2];
  const int vdg = tid >> 4;   // d-group: 8 d elems
  const int vkg = tid & 15;   // kv-group: 4 kv rows

  auto issue_loads = [&](int kt) {
#pragma unroll
    for (int i = 0; i < 4; i++) {
      int c = i * 256 + tid, row = c >> 4, c8 = c & 15;
      kreg[i] = *(const uint4*)(qkv + (tok0 + kt * 64 + row) * LD + 2048 + kvh * 128 + c8 * 8);
    }
#pragma unroll
    for (int r = 0; r < 4; r++)
      vreg[r] = *(const bf16x8*)(qkv + (tok0 + kt * 64 + vkg * 4 + r) * LD + 2560 +
                                 kvh * 128 + vdg * 8);
#pragma unroll
    for (int hh = 0; hh < 2; hh++)
      gvreg[hh] = g2t[(size_t)(h0 + hh) * 4096 + tok0 + kt * 64 + lane];
  };

  auto write_lds = [&]() {
#pragma unroll
    for (int i = 0; i < 4; i++) {
      int c = i * 256 + tid, row = c >> 4, c8 = c & 15;
      int eidx = (row * 128 + c8 * 8) ^ ((row & 7) << 3);
      *(uint4*)&sK[eidx] = kreg[i];
    }
#pragma unroll
    for (int e2 = 0; e2 < 8; e2++) {
      int d = vdg * 8 + e2;          // d & 7 == e2
      uint32_t lo = (uint32_t)(unsigned short)vreg[0][e2] |
                    ((uint32_t)(unsigned short)vreg[1][e2] << 16);
      uint32_t hi = (uint32_t)(unsigned short)vreg[2][e2] |
                    ((uint32_t)(unsigned short)vreg[3][e2] << 16);
      int eidx = (d * 64 + vkg * 4) ^ (e2 << 3);
      uint2 pk; pk.x = lo; pk.y = hi;
      *(uint2*)&sV[eidx] = pk;
    }
  };

  issue_loads(k0);
  for (int kt = k0; kt < k1; kt++) {
    __syncthreads();  // previous tile's LDS reads complete before overwrite
    write_lds();      // vmcnt wait lands here (data long arrived)
    float gv0 = gvreg[0], gv1 = gvreg[1];
    if (kt + 1 < k1) issue_loads(kt + 1);  // registers only; in flight across barrier+compute
    __syncthreads();  // LDS writes visible

    const bool diag = (kt == qt);
#pragma unroll
    for (int hh = 0; hh < 2; hh++) {
      // ---- QK^T (T5: raise wave priority through the MFMA cluster) ----
      f32x4 sc[4];
      __builtin_amdgcn_s_setprio(1);
#pragma unroll
      for (int ct = 0; ct < 4; ct++) {
        f32x4 acc = f32x4{0.f, 0.f, 0.f, 0.f};
#pragma unroll
        for (int dc = 0; dc < 4; dc++) {
          int row = ct * 16 + llo;
          bf16x8 kf = *(const bf16x8*)&sK[(row * 128 + dc * 32 + lhi * 8) ^ ((row & 7) << 3)];
          acc = __builtin_amdgcn_mfma_f32_16x16x32_bf16(qf[hh][dc], kf, acc, 0, 0, 0);
        }
        sc[ct] = acc;
      }
      __builtin_amdgcn_s_setprio(0);
      // ---- causal mask + online softmax, log2 domain, defer-max THR=8 ----
      float pm[4] = {-1e30f, -1e30f, -1e30f, -1e30f};
#pragma unroll
      for (int ct = 0; ct < 4; ct++) {
        int kv = kt * 64 + ct * 16 + llo;
#pragma unroll
        for (int r = 0; r < 4; r++) {
          float s_ = sc[ct][r];
          if (diag && kv > qrow0 + lhi * 4 + r) s_ = -1e30f;
          sc[ct][r] = s_;
          pm[r] = fmaxf(pm[r], s_);
        }
      }
#pragma unroll
      for (int r = 0; r < 4; r++) {
        float v = pm[r];
        v = fmaxf(v, __shfl_xor(v, 1));
        v = fmaxf(v, __shfl_xor(v, 2));
        v = fmaxf(v, __shfl_xor(v, 4));
        v = fmaxf(v, __shfl_xor(v, 8));
        pm[r] = v;
      }
      int need = 0;
#pragma unroll
      for (int r = 0; r < 4; r++) need |= (pm[r] > mrow[hh][r] + 8.f) ? 1 : 0;
      if (__any(need)) {
#pragma unroll
        for (int r = 0; r < 4; r++) {
          float mnew = fmaxf(mrow[hh][r], pm[r]);
          float al = fexp2(mrow[hh][r] - mnew);
          mrow[hh][r] = mnew;
          lrow[hh][r] *= al;
#pragma unroll
          for (int i = 0; i < 8; i++) oacc[hh][i][r] *= al;
        }
      }
      float gv = hh ? gv1 : gv0;
      float g2v[4];
#pragma unroll
      for (int ct = 0; ct < 4; ct++) g2v[ct] = __shfl(gv, ct * 16 + llo);
      float rs[4] = {0.f, 0.f, 0.f, 0.f};
#pragma unroll
      for (int ct = 0; ct < 4; ct++) {
#pragma unroll
        for (int r = 0; r < 4; r++) {
          float p = fexp2(sc[ct][r] - mrow[hh][r]);
          rs[r] += p;  // softmax denom uses UNGATED p
          sP[wave][hh][lhi * 4 + r][ct * 16 + llo] = tobf(p * g2v[ct]);
        }
      }
#pragma unroll
      for (int r = 0; r < 4; r++) {
        float v = rs[r];
        v += __shfl_xor(v, 1); v += __shfl_xor(v, 2); v += __shfl_xor(v, 4); v += __shfl_xor(v, 8);
        lrow[hh][r] += v;
      }
    }
    // ---- PV: both heads share each V fragment (T5 around MFMA cluster) ----
    __builtin_amdgcn_s_setprio(1);
#pragma unroll
    for (int kc = 0; kc < 2; kc++) {
      bf16x8 pf0 = *(const bf16x8*)&sP[wave][0][llo][kc * 32 + lhi * 8];
      bf16x8 pf1 = *(const bf16x8*)&sP[wave][1][llo][kc * 32 + lhi * 8];
#pragma unroll
      for (int dt = 0; dt < 8; dt++) {
        int d = dt * 16 + llo;
        bf16x8 vf = *(const bf16x8*)&sV[(d * 64 + kc * 32 + lhi * 8) ^ ((d & 7) << 3)];
        oacc[0][dt] = __builtin_amdgcn_mfma_f32_16x16x32_bf16(pf0, vf, oacc[0][dt], 0, 0, 0);
        oacc[1][dt] = __builtin_amdgcn_mfma_f32_16x16x32_bf16(pf1, vf, oacc[1][dt], 0, 0, 0);
      }
    }
    __builtin_amdgcn_s_setprio(0);
  }

  if (partial) {
    const int pid = pid_base(qt) + s;
#pragma unroll
    for (int hh = 0; hh < 2; hh++) {
      const int sub = (g * 2 + hp) * 2 + hh;
      uint2* dst = (uint2*)pO + (size_t)(pid * 32 + sub) * 2048;
#pragma unroll
      for (int dt = 0; dt < 8; dt++) {
        bf16 pk[4];
#pragma unroll
        for (int r = 0; r < 4; r++) pk[r] = tobf(oacc[hh][dt][r]);
        uint2 uu; __builtin_memcpy(&uu, pk, 8);
        dst[(wave * 8 + dt) * 64 + lane] = uu;
      }
      if (llo == 0) {
#pragma unroll
        for (int r = 0; r < 4; r++) {
          int row = wave * 16 + lhi * 4 + r;
          float* pm = pML + ((size_t)(pid * 32 + sub) * 64 + row) * 2;
          pm[0] = mrow[hh][r];
          pm[1] = lrow[hh][r];
        }
      }
    }
  } else {
#pragma unroll
    for (int hh = 0; hh < 2; hh++) {
      float inv[4];
#pragma unroll
      for (int r = 0; r < 4; r++) inv[r] = 1.f / lrow[hh][r];
      f32x4 o[8];
#pragma unroll
      for (int dt = 0; dt < 8; dt++)
#pragma unroll
        for (int r = 0; r < 4; r++) o[dt][r] = oacc[hh][dt][r] * inv[r];
      finalize_store(o, wave, lhi, llo, tid, h0 + hh, qt, tok0, g1t, lng, lnb, sK, aout);
    }
  }
}

// ---------------- combine ns partials (2..4) + LN + g1 gate ----------------
// 384 blocks; m values are in log2 domain (weights via raw v_exp_f32, matching split).
__global__ __launch_bounds__(256) void attn_combine_k(
    const bf16* __restrict__ pO, const float* __restrict__ pML,
    const float* __restrict__ g1t, const float* __restrict__ lng,
    const float* __restrict__ lnb, bf16* __restrict__ aout) {
  __shared__ bf16 stg[64 * 128];
  const int bid = blockIdx.x;
  const int g = bid & 7, j = bid >> 3;
  const int hp = j & 1, qtc = j >> 1;
  const int qt = 8 + qtc;
  const int ns = (qt < 16) ? 2 : (qt < 24) ? 3 : 4;
  const int p0id = pid_base(qt);
  const int b = g >> 2, kvh = g & 3, h0 = kvh * 4 + hp * 2;
  const int tid = threadIdx.x, wave = tid >> 6, lane = tid & 63;
  const int lhi = lane >> 4, llo = lane & 15;
  const size_t tok0 = (size_t)b * 2048;
#pragma unroll
  for (int hh = 0; hh < 2; hh++) {
    const int sub = (g * 2 + hp) * 2 + hh;
    float w[4][4], inv[4];
#pragma unroll
    for (int r = 0; r < 4; r++) {
      int row = wave * 16 + lhi * 4 + r;
      float m[4], l[4], ms = -1e30f;
#pragma unroll
      for (int sp = 0; sp < 4; sp++)
        if (sp < ns) {
          const float* q = pML + ((size_t)((p0id + sp) * 32 + sub) * 64 + row) * 2;
          m[sp] = q[0]; l[sp] = q[1];
          ms = fmaxf(ms, m[sp]);
        }
      float L = 0.f;
#pragma unroll
      for (int sp = 0; sp < 4; sp++)
        if (sp < ns) { w[sp][r] = fexp2(m[sp] - ms); L += w[sp][r] * l[sp]; }
      inv[r] = 1.f / L;
    }
    f32x4 o[8];
#pragma unroll
    for (int dt = 0; dt < 8; dt++) {
      f32x4 a = f32x4{0.f, 0.f, 0.f, 0.f};
#pragma unroll
      for (int sp = 0; sp < 4; sp++)
        if (sp < ns) {
          uint2 uu = ((const uint2*)pO + (size_t)((p0id + sp) * 32 + sub) * 2048)
                         [(wave * 8 + dt) * 64 + lane];
          bf16 pk[4]; __builtin_memcpy(pk, &uu, 8);
#pragma unroll
          for (int r = 0; r < 4; r++) a[r] += w[sp][r] * tof(pk[r]);
        }
#pragma unroll
      for (int r = 0; r < 4; r++) o[dt][r] = a[r] * inv[r];
    }
    finalize_store(o, wave, lhi, llo, tid, h0 + hh, qt, tok0, g1t, lng, lnb, stg, aout);
  }
}

// ---------------- launch ----------------
extern "C" void kernel_launch(void* const* d_in, const int* in_sizes, int n_in,
                              void* d_out, int out_size, void* d_ws, size_t ws_size,
                              hipStream_t stream) {
  (void)in_sizes; (void)n_in; (void)out_size; (void)ws_size;
  const float* X   = (const float*)d_in[0];
  const int*   pos = (const int*)d_in[1];
  const float* Wq  = (const float*)d_in[2];
  const float* Wk  = (const float*)d_in[3];
  const float* Wv  = (const float*)d_in[4];
  const float* Wo  = (const float*)d_in[5];
  const float* Wg1 = (const float*)d_in[6];
  const float* bg1 = (const float*)d_in[7];
  const float* Wg2 = (const float*)d_in[8];
  const float* bg2 = (const float*)d_in[9];
  const float* lng = (const float*)d_in[10];
  const float* lnb = (const float*)d_in[11];

  char* ws = (char*)d_ws;
  size_t off = 0;
  auto alloc = [&](size_t bytes) {
    void* p = ws + off;
    off += (bytes + 255) & ~(size_t)255;
    return p;
  };
  bf16*  WT   = (bf16*)alloc(3200ull * 2048 * 2);   // [Wq^T; Wk^T; Wv^T; Wg1^T; Wg2^T; pad]
  bf16*  WoT  = (bf16*)alloc(2048ull * 2048 * 2);
  bf16*  Xbf  = (bf16*)alloc(4096ull * 2048 * 2);
  bf16*  qkv  = (bf16*)alloc(4096ull * 3072 * 2);
  bf16*  attn = (bf16*)alloc(4096ull * 2048 * 2);
  float* cosT = (float*)alloc(2048ull * 64 * 4);
  float* sinT = (float*)alloc(2048ull * 64 * 4);
  float* g1t  = (float*)alloc(16ull * 4096 * 4);    // [head][token]
  float* g2t  = (float*)alloc(16ull * 4096 * 4);
  bf16*  pO   = (bf16*)alloc(80ull * 32 * 2048 * 8);  // [pid][sub] bf16x4-coalesced partials
  float* pML  = (float*)alloc(80ull * 32 * 64 * 2 * 4);

  // all prep in one launch: weight transposes (128B-segment writes), X cast,
  // rope tables, gate-weight transpose
  prep_all_k<<<5152, 256, 0, stream>>>(X, pos, Wq, Wk, Wv, Wo, Wg1, Wg2,
                                       WT, WoT, Xbf, cosT, sinT);

  // [qkv | g1t | g2t] = Xbf @ WT^T  (4096 x 3200), RoPE + Q log2-prescale fused
  gemm_qkv_k<<<800, 256, 0, stream>>>(Xbf, WT, qkv, g1t, g2t, bg1, bg2, cosT, sinT);
  attn_split_k<<<1280, 256, 0, stream>>>(qkv, g2t, g1t, lng, lnb, pO, pML, attn);
  attn_combine_k<<<384, 256, 0, stream>>>(pO, pML, g1t, lng, lnb, attn);
  // out = attn @ Wo  (4096 x 2048), fp32
  gemm_out_k<<<512, 256, 0, stream>>>(attn, WoT, (float*)d_out, 2048, 2048);
}